// Round 1
// baseline (1050.269 us; speedup 1.0000x reference)
//
#include <hip/hip_runtime.h>
#include <math.h>

// Problem constants (from reference): B=8, C=512, CI=128, H=W=64
constexpr int Cc  = 512;
constexpr int CIc = 128;
constexpr int Bc  = 8;
constexpr int Nc  = 4096;   // H*W
constexpr int Mc  = 1024;   // (H/2)*(W/2)

// ---------------------------------------------------------------------------
// Kernel 1: theta = conv1x1(x, theta_w) + theta_b   -> [B, CI, N]
// grid (N/64, B), block (64,4). Each thread: 32 ci x 1 n.
// ---------------------------------------------------------------------------
__global__ __launch_bounds__(256) void k_conv_theta(
    const float* __restrict__ x, const float* __restrict__ w,
    const float* __restrict__ bias, float* __restrict__ out) {
  __shared__ float xs[16][64];     // [c][n]
  __shared__ float wst[16][132];   // [c][ci], padded
  const int n0 = blockIdx.x * 64;
  const int b  = blockIdx.y;
  const int tx = threadIdx.x, ty = threadIdx.y;
  const int tid = ty * 64 + tx;
  float acc[32];
#pragma unroll
  for (int j = 0; j < 32; ++j) acc[j] = 0.f;
  const float* xb = x + (size_t)b * Cc * Nc + n0;
  for (int c0 = 0; c0 < Cc; c0 += 16) {
    __syncthreads();
    // x tile: 1024 elements as float4 (coalesced)
    {
      int cc = tid >> 4, nq = tid & 15;
      *(float4*)&xs[cc][nq * 4] =
          *(const float4*)&xb[(size_t)(c0 + cc) * Nc + nq * 4];
    }
    // w tile transposed: 2048 elements scalar (coalesced read, 2-way LDS write)
    for (int i = tid; i < 2048; i += 256) {
      int ci = i >> 4, cc = i & 15;
      wst[cc][ci] = w[ci * Cc + c0 + cc];
    }
    __syncthreads();
#pragma unroll
    for (int cc = 0; cc < 16; ++cc) {
      float xv = xs[cc][tx];
      const float4* wr = (const float4*)&wst[cc][ty * 32];
#pragma unroll
      for (int j4 = 0; j4 < 8; ++j4) {
        float4 wv = wr[j4];
        acc[j4 * 4 + 0] += wv.x * xv;
        acc[j4 * 4 + 1] += wv.y * xv;
        acc[j4 * 4 + 2] += wv.z * xv;
        acc[j4 * 4 + 3] += wv.w * xv;
      }
    }
  }
  float* ob = out + (size_t)b * CIc * Nc + n0;
#pragma unroll
  for (int j = 0; j < 32; ++j) {
    int ci = ty * 32 + j;
    ob[(size_t)ci * Nc + tx] = acc[j] + bias[ci];
  }
}

// ---------------------------------------------------------------------------
// Kernel 2: g = maxpool2(conv1x1(x,g_w))+g_b ; phi likewise  -> [B, CI, M]
// grid (4, 32, B) = (ci-group, h2, b), block (32,8).
// Each thread: 4 ci x 1 pooled position x {g,phi}; pools 4 spatial convs.
// ---------------------------------------------------------------------------
__global__ __launch_bounds__(256) void k_conv_pool_gphi(
    const float* __restrict__ x,
    const float* __restrict__ gw, const float* __restrict__ gbias,
    const float* __restrict__ pw, const float* __restrict__ pbias,
    float* __restrict__ outg, float* __restrict__ outp) {
  __shared__ float xs[16][128];    // [c][two spatial rows of 64]
  __shared__ float wgs[16][36];    // [c][ci_local], padded
  __shared__ float wps[16][36];
  const int cg = blockIdx.x, h2 = blockIdx.y, b = blockIdx.z;
  const int tx = threadIdx.x, ty = threadIdx.y;   // tx = w2
  const int tid = ty * 32 + tx;
  float ag[4][4], ap[4][4];
#pragma unroll
  for (int j = 0; j < 4; ++j)
#pragma unroll
    for (int q = 0; q < 4; ++q) { ag[j][q] = 0.f; ap[j][q] = 0.f; }
  // rows 2*h2 and 2*h2+1 are contiguous: 128 floats starting at h2*128
  const float* xb = x + (size_t)b * Cc * Nc + h2 * 128;
  for (int c0 = 0; c0 < Cc; c0 += 16) {
    __syncthreads();
    for (int i = tid; i < 512; i += 256) {   // 2048 el as float4, 2 per thread
      int cc = i >> 5, oq = i & 31;
      *(float4*)&xs[cc][oq * 4] =
          *(const float4*)&xb[(size_t)(c0 + cc) * Nc + oq * 4];
    }
    for (int i = tid; i < 512; i += 256) {   // w tiles: 32 ci x 16 c each
      int ci = i >> 4, cc = i & 15;
      wgs[cc][ci] = gw[(cg * 32 + ci) * Cc + c0 + cc];
      wps[cc][ci] = pw[(cg * 32 + ci) * Cc + c0 + cc];
    }
    __syncthreads();
#pragma unroll
    for (int cc = 0; cc < 16; ++cc) {
      float x00 = xs[cc][2 * tx], x01 = xs[cc][2 * tx + 1];
      float x10 = xs[cc][64 + 2 * tx], x11 = xs[cc][64 + 2 * tx + 1];
      float4 wg = *(const float4*)&wgs[cc][ty * 4];
      float4 wp = *(const float4*)&wps[cc][ty * 4];
      float wgj[4] = {wg.x, wg.y, wg.z, wg.w};
      float wpj[4] = {wp.x, wp.y, wp.z, wp.w};
#pragma unroll
      for (int j = 0; j < 4; ++j) {
        ag[j][0] += wgj[j] * x00; ag[j][1] += wgj[j] * x01;
        ag[j][2] += wgj[j] * x10; ag[j][3] += wgj[j] * x11;
        ap[j][0] += wpj[j] * x00; ap[j][1] += wpj[j] * x01;
        ap[j][2] += wpj[j] * x10; ap[j][3] += wpj[j] * x11;
      }
    }
  }
  const int m = h2 * 32 + tx;
#pragma unroll
  for (int j = 0; j < 4; ++j) {
    int ci = cg * 32 + ty * 4 + j;
    float gv = fmaxf(fmaxf(ag[j][0], ag[j][1]), fmaxf(ag[j][2], ag[j][3])) + gbias[ci];
    float pv = fmaxf(fmaxf(ap[j][0], ap[j][1]), fmaxf(ap[j][2], ap[j][3])) + pbias[ci];
    outg[(size_t)b * CIc * Mc + (size_t)ci * Mc + m] = gv;
    outp[(size_t)b * CIc * Mc + (size_t)ci * Mc + m] = pv;
  }
}

// ---------------------------------------------------------------------------
// Kernel 3: flash attention.  y[b,ci,n] = sum_m softmax_m(theta.phi)[n,m] g[ci,m]
// grid (N/32, B), block (64,4). Wave ty owns query rows {ty+4k}, k=0..7.
// phi tile and g tile time-share one LDS buffer.
// ---------------------------------------------------------------------------
__global__ __launch_bounds__(256) void k_attn(
    const float* __restrict__ theta, const float* __restrict__ phi,
    const float* __restrict__ g, float* __restrict__ y) {
  __shared__ float ths[32 * 130];  // theta^T [n][c], pad 2
  __shared__ float kvs[64 * 130];  // phi [c][m] (c*64+m)  OR  g [m][ci] (m*130+ci)
  __shared__ float ps[32 * 64];    // P tile [n][m]  (wave-private rows)
  const int n0 = blockIdx.x * 32;
  const int b  = blockIdx.y;
  const int tx = threadIdx.x, ty = threadIdx.y;
  const int tid = ty * 64 + tx;
  const float* thb = theta + (size_t)b * CIc * Nc + n0;
  const float* phb = phi + (size_t)b * CIc * Mc;
  const float* gbp = g + (size_t)b * CIc * Mc;
  // theta tile, transposed (float4 global read, scattered 2-way LDS write)
  for (int i = tid; i < 1024; i += 256) {
    int c = i >> 3, nq = i & 7;
    float4 v = *(const float4*)&thb[(size_t)c * Nc + nq * 4];
    ths[(nq * 4 + 0) * 130 + c] = v.x;
    ths[(nq * 4 + 1) * 130 + c] = v.y;
    ths[(nq * 4 + 2) * 130 + c] = v.z;
    ths[(nq * 4 + 3) * 130 + c] = v.w;
  }
  float acc0[8], acc1[8], run_m[8], run_l[8];
#pragma unroll
  for (int k = 0; k < 8; ++k) { acc0[k] = 0.f; acc1[k] = 0.f; run_m[k] = -1e30f; run_l[k] = 0.f; }

  for (int t = 0; t < Mc / 64; ++t) {
    __syncthreads();  // kvs free (iter 0: theta tile also ready)
    // load phi tile [128][64]
    for (int i = tid; i < 2048; i += 256) {
      int c = i >> 4, mq = i & 15;
      *(float4*)&kvs[c * 64 + mq * 4] =
          *(const float4*)&phb[(size_t)c * Mc + t * 64 + mq * 4];
    }
    __syncthreads();
    // f[k] = theta_row(ty+4k) . phi_col(tx)
    float f[8];
#pragma unroll
    for (int k = 0; k < 8; ++k) f[k] = 0.f;
    for (int c = 0; c < 128; c += 2) {
      float p0 = kvs[c * 64 + tx], p1 = kvs[(c + 1) * 64 + tx];
#pragma unroll
      for (int k = 0; k < 8; ++k) {
        float2 th = *(const float2*)&ths[(ty + 4 * k) * 130 + c];
        f[k] += th.x * p0 + th.y * p1;
      }
    }
    // online softmax (full-wave reductions)
#pragma unroll
    for (int k = 0; k < 8; ++k) {
      float mx = f[k];
#pragma unroll
      for (int off = 32; off; off >>= 1) mx = fmaxf(mx, __shfl_xor(mx, off));
      float nm = fmaxf(run_m[k], mx);
      float sc = __expf(run_m[k] - nm);
      float pv = __expf(f[k] - nm);
      float sum = pv;
#pragma unroll
      for (int off = 32; off; off >>= 1) sum += __shfl_xor(sum, off);
      run_l[k] = run_l[k] * sc + sum;
      run_m[k] = nm;
      ps[(ty + 4 * k) * 64 + tx] = pv;
      acc0[k] *= sc;
      acc1[k] *= sc;
    }
    __syncthreads();  // all waves done reading phi from kvs
    // load g tile transposed [m][ci]
    for (int i = tid; i < 2048; i += 256) {
      int ci = i >> 4, mq = i & 15;
      float4 v = *(const float4*)&gbp[(size_t)ci * Mc + t * 64 + mq * 4];
      kvs[(mq * 4 + 0) * 130 + ci] = v.x;
      kvs[(mq * 4 + 1) * 130 + ci] = v.y;
      kvs[(mq * 4 + 2) * 130 + ci] = v.z;
      kvs[(mq * 4 + 3) * 130 + ci] = v.w;
    }
    __syncthreads();
    // y accumulation: acc0 -> ci=tx, acc1 -> ci=tx+64
    for (int mm = 0; mm < 64; mm += 2) {
      float g00 = kvs[mm * 130 + tx],       g01 = kvs[mm * 130 + 64 + tx];
      float g10 = kvs[(mm + 1) * 130 + tx], g11 = kvs[(mm + 1) * 130 + 64 + tx];
#pragma unroll
      for (int k = 0; k < 8; ++k) {
        float2 pv = *(const float2*)&ps[(ty + 4 * k) * 64 + mm];
        acc0[k] += pv.x * g00 + pv.y * g10;
        acc1[k] += pv.x * g01 + pv.y * g11;
      }
    }
  }
  // epilogue: normalize + transpose-stage in LDS for coalesced global write
  __syncthreads();
#pragma unroll
  for (int k = 0; k < 8; ++k) {
    int nn = ty + 4 * k;
    kvs[tx * 33 + nn]        = acc0[k] / run_l[k];
    kvs[(tx + 64) * 33 + nn] = acc1[k] / run_l[k];
  }
  __syncthreads();
  float* yb = y + (size_t)b * CIc * Nc + n0;
  for (int i = tid; i < 128 * 32; i += 256) {
    int ci = i >> 5, nn = i & 31;
    yb[(size_t)ci * Nc + nn] = kvs[ci * 33 + nn];
  }
}

// ---------------------------------------------------------------------------
// Kernel 4: W_y = conv1x1(y, W_w)+W_b; channel LayerNorm; +x residual
// grid (N/16, B), block 256. Thread t owns channels {t, t+256} x 16 positions.
// ---------------------------------------------------------------------------
__global__ __launch_bounds__(256) void k_wconv_ln(
    const float* __restrict__ y, const float* __restrict__ ww,
    const float* __restrict__ wbias, const float* __restrict__ gamma,
    const float* __restrict__ beta, const float* __restrict__ x,
    float* __restrict__ out) {
  __shared__ float ys[128 * 16];   // [ci][p]
  __shared__ float red[2][4][16];  // [sum|sumsq][wave][p]
  const int n0 = blockIdx.x * 16;
  const int b  = blockIdx.y;
  const int t  = threadIdx.x;
  const float* yb = y + (size_t)b * CIc * Nc + n0;
  for (int i = t; i < 512; i += 256) {   // 2048 el as float4
    int ci = i >> 2, pq = i & 3;
    *(float4*)&ys[ci * 16 + pq * 4] =
        *(const float4*)&yb[(size_t)ci * Nc + pq * 4];
  }
  __syncthreads();
  float acc0[16], acc1[16];
  const float b0 = wbias[t], b1 = wbias[t + 256];
#pragma unroll
  for (int p = 0; p < 16; ++p) { acc0[p] = b0; acc1[p] = b1; }
  const float4* w0p = (const float4*)(ww + (size_t)t * CIc);
  const float4* w1p = (const float4*)(ww + (size_t)(t + 256) * CIc);
  for (int c4 = 0; c4 < 32; ++c4) {
    float4 w0 = w0p[c4], w1 = w1p[c4];
    const float* yr = &ys[c4 * 4 * 16];
#pragma unroll
    for (int p = 0; p < 16; ++p) {
      float a = yr[p], bb = yr[16 + p], cc = yr[32 + p], dd = yr[48 + p];
      acc0[p] += w0.x * a + w0.y * bb + w0.z * cc + w0.w * dd;
      acc1[p] += w1.x * a + w1.y * bb + w1.z * cc + w1.w * dd;
    }
  }
  const int lane = t & 63, wv = t >> 6;
#pragma unroll
  for (int p = 0; p < 16; ++p) {
    float sv = acc0[p] + acc1[p];
    float qv = acc0[p] * acc0[p] + acc1[p] * acc1[p];
#pragma unroll
    for (int off = 32; off; off >>= 1) {
      sv += __shfl_xor(sv, off);
      qv += __shfl_xor(qv, off);
    }
    if (lane == 0) { red[0][wv][p] = sv; red[1][wv][p] = qv; }
  }
  __syncthreads();
  const float ga0 = gamma[t], be0 = beta[t], ga1 = gamma[t + 256], be1 = beta[t + 256];
  const size_t base0 = (size_t)b * Cc * Nc + (size_t)t * Nc + n0;
  const size_t base1 = (size_t)b * Cc * Nc + (size_t)(t + 256) * Nc + n0;
#pragma unroll
  for (int p = 0; p < 16; ++p) {
    float s = red[0][0][p] + red[0][1][p] + red[0][2][p] + red[0][3][p];
    float q = red[1][0][p] + red[1][1][p] + red[1][2][p] + red[1][3][p];
    float mu  = s * (1.f / 512.f);
    float var = q * (1.f / 512.f) - mu * mu;
    float rs  = rsqrtf(var + 1e-5f);
    out[base0 + p] = (acc0[p] - mu) * rs * ga0 + be0 + x[base0 + p];
    out[base1 + p] = (acc1[p] - mu) * rs * ga1 + be1 + x[base1 + p];
  }
}

// ---------------------------------------------------------------------------
extern "C" void kernel_launch(void* const* d_in, const int* in_sizes, int n_in,
                              void* d_out, int out_size, void* d_ws, size_t ws_size,
                              hipStream_t stream) {
  const float* x       = (const float*)d_in[0];
  const float* g_w     = (const float*)d_in[1];
  const float* g_b     = (const float*)d_in[2];
  const float* phi_w   = (const float*)d_in[3];
  const float* phi_b   = (const float*)d_in[4];
  const float* theta_w = (const float*)d_in[5];
  const float* theta_b = (const float*)d_in[6];
  const float* W_w     = (const float*)d_in[7];
  const float* W_b     = (const float*)d_in[8];
  const float* ln_g    = (const float*)d_in[9];
  const float* ln_b    = (const float*)d_in[10];
  float* out = (float*)d_out;

  // workspace layout (fp32): theta [B,CI,N] | g [B,CI,M] | phi [B,CI,M] | y [B,CI,N]
  float* theta = (float*)d_ws;
  float* gbuf  = theta + (size_t)Bc * CIc * Nc;
  float* pbuf  = gbuf + (size_t)Bc * CIc * Mc;
  float* ybuf  = pbuf + (size_t)Bc * CIc * Mc;
  // total: 40 MiB — assumed <= ws_size

  k_conv_theta<<<dim3(Nc / 64, Bc), dim3(64, 4), 0, stream>>>(x, theta_w, theta_b, theta);
  k_conv_pool_gphi<<<dim3(4, 32, Bc), dim3(32, 8), 0, stream>>>(x, g_w, g_b, phi_w, phi_b, gbuf, pbuf);
  k_attn<<<dim3(Nc / 32, Bc), dim3(64, 4), 0, stream>>>(theta, pbuf, gbuf, ybuf);
  k_wconv_ln<<<dim3(Nc / 16, Bc), dim3(256), 0, stream>>>(ybuf, W_w, W_b, ln_g, ln_b, x, out);
}

// Round 2
// 470.516 us; speedup vs baseline: 2.2322x; 2.2322x over previous
//
#include <hip/hip_runtime.h>
#include <math.h>

// Problem constants (from reference): B=8, C=512, CI=128, H=W=64
constexpr int Cc  = 512;
constexpr int CIc = 128;
constexpr int Bc  = 8;
constexpr int Nc  = 4096;   // H*W
constexpr int Mc  = 1024;   // (H/2)*(W/2)

typedef __bf16 bf16x8 __attribute__((ext_vector_type(8)));
typedef float  f32x4  __attribute__((ext_vector_type(4)));

__device__ __forceinline__ unsigned short f2bf(float f) {
  unsigned u = __float_as_uint(f);
  u += 0x7fffu + ((u >> 16) & 1u);
  return (unsigned short)(u >> 16);
}
__device__ __forceinline__ float bf2f(unsigned short h) {
  return __uint_as_float((unsigned)h << 16);
}

// ---------------------------------------------------------------------------
// Kernel 1: theta_t[b][n][ci] = bf16( conv1x1(x, theta_w) + theta_b )
// grid (N/64, B), block (64,4). Each thread: 32 ci x 1 n.
// ---------------------------------------------------------------------------
__global__ __launch_bounds__(256) void k_conv_theta(
    const float* __restrict__ x, const float* __restrict__ w,
    const float* __restrict__ bias, unsigned short* __restrict__ theta_t) {
  __shared__ float xs[16][64];     // [c][n]
  __shared__ float wst[16][132];   // [c][ci], padded
  const int n0 = blockIdx.x * 64;
  const int b  = blockIdx.y;
  const int tx = threadIdx.x, ty = threadIdx.y;
  const int tid = ty * 64 + tx;
  float acc[32];
#pragma unroll
  for (int j = 0; j < 32; ++j) acc[j] = 0.f;
  const float* xb = x + (size_t)b * Cc * Nc + n0;
  for (int c0 = 0; c0 < Cc; c0 += 16) {
    __syncthreads();
    {
      int cc = tid >> 4, nq = tid & 15;
      *(float4*)&xs[cc][nq * 4] =
          *(const float4*)&xb[(size_t)(c0 + cc) * Nc + nq * 4];
    }
    for (int i = tid; i < 2048; i += 256) {
      int ci = i >> 4, cc = i & 15;
      wst[cc][ci] = w[ci * Cc + c0 + cc];
    }
    __syncthreads();
#pragma unroll
    for (int cc = 0; cc < 16; ++cc) {
      float xv = xs[cc][tx];
      const float4* wr = (const float4*)&wst[cc][ty * 32];
#pragma unroll
      for (int j4 = 0; j4 < 8; ++j4) {
        float4 wv = wr[j4];
        acc[j4 * 4 + 0] += wv.x * xv;
        acc[j4 * 4 + 1] += wv.y * xv;
        acc[j4 * 4 + 2] += wv.z * xv;
        acc[j4 * 4 + 3] += wv.w * xv;
      }
    }
  }
  unsigned short* ob =
      theta_t + (((size_t)(b * Nc + n0 + tx)) << 7) + ty * 32;
#pragma unroll
  for (int j4 = 0; j4 < 8; ++j4) {
    ushort4 pk;
    pk.x = f2bf(acc[j4 * 4 + 0] + bias[ty * 32 + j4 * 4 + 0]);
    pk.y = f2bf(acc[j4 * 4 + 1] + bias[ty * 32 + j4 * 4 + 1]);
    pk.z = f2bf(acc[j4 * 4 + 2] + bias[ty * 32 + j4 * 4 + 2]);
    pk.w = f2bf(acc[j4 * 4 + 3] + bias[ty * 32 + j4 * 4 + 3]);
    *(ushort4*)(ob + j4 * 4) = pk;
  }
}

// ---------------------------------------------------------------------------
// Kernel 2: g[b][ci][m] (bf16), phi_t[b][m][ci] (bf16) with 2x2 maxpool.
// grid (4, 32, B) = (ci-group, h2, b), block (32,8).
// ---------------------------------------------------------------------------
__global__ __launch_bounds__(256) void k_conv_pool_gphi(
    const float* __restrict__ x,
    const float* __restrict__ gw, const float* __restrict__ gbias,
    const float* __restrict__ pw, const float* __restrict__ pbias,
    unsigned short* __restrict__ outg, unsigned short* __restrict__ phi_t) {
  __shared__ float xs[16][128];
  __shared__ float wgs[16][36];
  __shared__ float wps[16][36];
  const int cg = blockIdx.x, h2 = blockIdx.y, b = blockIdx.z;
  const int tx = threadIdx.x, ty = threadIdx.y;   // tx = w2
  const int tid = ty * 32 + tx;
  float ag[4][4], ap[4][4];
#pragma unroll
  for (int j = 0; j < 4; ++j)
#pragma unroll
    for (int q = 0; q < 4; ++q) { ag[j][q] = 0.f; ap[j][q] = 0.f; }
  const float* xb = x + (size_t)b * Cc * Nc + h2 * 128;
  for (int c0 = 0; c0 < Cc; c0 += 16) {
    __syncthreads();
    for (int i = tid; i < 512; i += 256) {
      int cc = i >> 5, oq = i & 31;
      *(float4*)&xs[cc][oq * 4] =
          *(const float4*)&xb[(size_t)(c0 + cc) * Nc + oq * 4];
    }
    for (int i = tid; i < 512; i += 256) {
      int ci = i >> 4, cc = i & 15;
      wgs[cc][ci] = gw[(cg * 32 + ci) * Cc + c0 + cc];
      wps[cc][ci] = pw[(cg * 32 + ci) * Cc + c0 + cc];
    }
    __syncthreads();
#pragma unroll
    for (int cc = 0; cc < 16; ++cc) {
      float x00 = xs[cc][2 * tx], x01 = xs[cc][2 * tx + 1];
      float x10 = xs[cc][64 + 2 * tx], x11 = xs[cc][64 + 2 * tx + 1];
      float4 wg = *(const float4*)&wgs[cc][ty * 4];
      float4 wp = *(const float4*)&wps[cc][ty * 4];
      float wgj[4] = {wg.x, wg.y, wg.z, wg.w};
      float wpj[4] = {wp.x, wp.y, wp.z, wp.w};
#pragma unroll
      for (int j = 0; j < 4; ++j) {
        ag[j][0] += wgj[j] * x00; ag[j][1] += wgj[j] * x01;
        ag[j][2] += wgj[j] * x10; ag[j][3] += wgj[j] * x11;
        ap[j][0] += wpj[j] * x00; ap[j][1] += wpj[j] * x01;
        ap[j][2] += wpj[j] * x10; ap[j][3] += wpj[j] * x11;
      }
    }
  }
  const int m = h2 * 32 + tx;
  ushort4 pk;
  unsigned short pv4[4];
#pragma unroll
  for (int j = 0; j < 4; ++j) {
    int ci = cg * 32 + ty * 4 + j;
    float gvv = fmaxf(fmaxf(ag[j][0], ag[j][1]), fmaxf(ag[j][2], ag[j][3])) + gbias[ci];
    float pvv = fmaxf(fmaxf(ap[j][0], ap[j][1]), fmaxf(ap[j][2], ap[j][3])) + pbias[ci];
    outg[(((size_t)(b * CIc + ci)) << 10) + m] = f2bf(gvv);
    pv4[j] = f2bf(pvv);
  }
  pk.x = pv4[0]; pk.y = pv4[1]; pk.z = pv4[2]; pk.w = pv4[3];
  *(ushort4*)(phi_t + (((size_t)(b * Mc + m)) << 7) + cg * 32 + ty * 4) = pk;
}

// ---------------------------------------------------------------------------
// Kernel 3: MFMA flash attention.
//   theta_t [B][N][128] bf16 (Q), phi_t [B][M][128] bf16 (K),
//   g [B][128][M] bf16 (V) -> y_t [B][N][128] bf16.
// grid (N/64, B), block 256 (4 waves x 16 q-rows each). KV tiles of 64.
// MFMA 16x16x32 bf16: A lane: row=l%16, k=8*(l/16)+j (contiguous 8);
// B lane: col=l%16, k=8*(l/16)+j; D lane: col=l&15, row=4*(l>>4)+reg.
// ---------------------------------------------------------------------------
__global__ __launch_bounds__(256) void k_attn_mfma(
    const unsigned short* __restrict__ theta_t,
    const unsigned short* __restrict__ phi_t,
    const unsigned short* __restrict__ gv,
    unsigned short* __restrict__ y_t) {
  __shared__ __align__(16) char Ks[64 * 256];   // K tile [m][c] bf16, swizzled rows of 256B
  __shared__ __align__(16) char Vs[128 * 128];  // V tile [ci][m] bf16, swizzled rows of 128B
  __shared__ __align__(16) unsigned short Ps[4][16][72];  // per-wave P tile, 144B rows
  const int b = blockIdx.y, n0 = blockIdx.x * 64;
  const int tid = threadIdx.x;
  const int w = tid >> 6, l = tid & 63;
  const int lr = l & 15, lg = l >> 4;

  // Q fragments: rows n0 + w*16 + lr, k-tiles of 32 channels
  bf16x8 qf[4];
  {
    const unsigned short* qp =
        theta_t + (((size_t)(b * Nc + n0 + w * 16 + lr)) << 7);
#pragma unroll
    for (int kk = 0; kk < 4; ++kk)
      qf[kk] = *(const bf16x8*)(qp + kk * 32 + lg * 8);
  }
  f32x4 of[8];
#pragma unroll
  for (int ct = 0; ct < 8; ++ct) of[ct] = (f32x4){0.f, 0.f, 0.f, 0.f};
  float run_m[4], run_l[4];
#pragma unroll
  for (int r = 0; r < 4; ++r) { run_m[r] = -1e30f; run_l[r] = 0.f; }

  for (int t = 0; t < Mc / 64; ++t) {
    __syncthreads();  // previous tile's LDS reads complete
    // stage K tile: phi_t rows t*64..t*64+63 (128 bf16 each) -> Ks swizzled
    {
      const unsigned short* kp = phi_t + (((size_t)(b * Mc + t * 64)) << 7);
#pragma unroll
      for (int it = 0; it < 4; ++it) {
        int i = it * 256 + tid;
        int r = i >> 4, cl = i & 15;
        bf16x8 v = *(const bf16x8*)(kp + (r << 7) + cl * 8);
        *(bf16x8*)(Ks + r * 256 + ((cl * 16) ^ ((r & 7) << 4))) = v;
      }
    }
    // stage V tile: g[b][ci][t*64..+63] -> Vs swizzled
    {
      const unsigned short* vp = gv + (((size_t)b) << 17) + t * 64;
#pragma unroll
      for (int it = 0; it < 4; ++it) {
        int i = it * 256 + tid;
        int ci = i >> 3, cl = i & 7;
        bf16x8 v = *(const bf16x8*)(vp + (ci << 10) + cl * 8);
        *(bf16x8*)(Vs + ci * 128 + ((cl * 16) ^ ((ci & 7) << 4))) = v;
      }
    }
    __syncthreads();
    // QK^T: S strip [16 n x 64 m] per wave
    f32x4 sm[4];
#pragma unroll
    for (int mt = 0; mt < 4; ++mt) {
      f32x4 s = (f32x4){0.f, 0.f, 0.f, 0.f};
#pragma unroll
      for (int kk = 0; kk < 4; ++kk) {
        bf16x8 kf = *(const bf16x8*)(
            Ks + (mt * 16 + lr) * 256 + ((kk * 64 + lg * 16) ^ ((lr & 7) << 4)));
        s = __builtin_amdgcn_mfma_f32_16x16x32_bf16(qf[kk], kf, s, 0, 0, 0);
      }
      sm[mt] = s;
    }
    // online softmax (rows 4*lg+reg live in the 16 lanes of group lg)
#pragma unroll
    for (int reg = 0; reg < 4; ++reg) {
      float mx = fmaxf(fmaxf(sm[0][reg], sm[1][reg]), fmaxf(sm[2][reg], sm[3][reg]));
      mx = fmaxf(mx, __shfl_xor(mx, 1));
      mx = fmaxf(mx, __shfl_xor(mx, 2));
      mx = fmaxf(mx, __shfl_xor(mx, 4));
      mx = fmaxf(mx, __shfl_xor(mx, 8));
      float nm = fmaxf(run_m[reg], mx);
      float sc = __expf(run_m[reg] - nm);
      run_m[reg] = nm;
      float rs = 0.f;
#pragma unroll
      for (int mt = 0; mt < 4; ++mt) {
        float p = __expf(sm[mt][reg] - nm);
        Ps[w][lg * 4 + reg][mt * 16 + lr] = f2bf(p);
        rs += p;
      }
      rs += __shfl_xor(rs, 1);
      rs += __shfl_xor(rs, 2);
      rs += __shfl_xor(rs, 4);
      rs += __shfl_xor(rs, 8);
      run_l[reg] = run_l[reg] * sc + rs;
#pragma unroll
      for (int ct = 0; ct < 8; ++ct) of[ct][reg] *= sc;
    }
    // PV: O strip [16 n x 128 ci] per wave (Ps is wave-private: no barrier)
    bf16x8 pa0 = *(const bf16x8*)(&Ps[w][lr][lg * 8]);
    bf16x8 pa1 = *(const bf16x8*)(&Ps[w][lr][32 + lg * 8]);
#pragma unroll
    for (int ct = 0; ct < 8; ++ct) {
      bf16x8 vf0 = *(const bf16x8*)(
          Vs + (ct * 16 + lr) * 128 + ((lg * 16) ^ ((lr & 7) << 4)));
      of[ct] = __builtin_amdgcn_mfma_f32_16x16x32_bf16(pa0, vf0, of[ct], 0, 0, 0);
      bf16x8 vf1 = *(const bf16x8*)(
          Vs + (ct * 16 + lr) * 128 + ((64 + lg * 16) ^ ((lr & 7) << 4)));
      of[ct] = __builtin_amdgcn_mfma_f32_16x16x32_bf16(pa1, vf1, of[ct], 0, 0, 0);
    }
  }
  // epilogue: normalize, stage strip in LDS (reuse Ks), coalesced bf16 write
  float invl[4];
#pragma unroll
  for (int reg = 0; reg < 4; ++reg) invl[reg] = 1.f / run_l[reg];
  __syncthreads();
  unsigned short* Ys = (unsigned short*)Ks;
#pragma unroll
  for (int ct = 0; ct < 8; ++ct)
#pragma unroll
    for (int reg = 0; reg < 4; ++reg)
      Ys[(w * 16 + lg * 4 + reg) * 128 + ct * 16 + lr] =
          f2bf(of[ct][reg] * invl[reg]);
  __syncthreads();
#pragma unroll
  for (int it = 0; it < 4; ++it) {
    int i = it * 256 + tid;
    int r = i >> 4, cl = i & 15;
    *(bf16x8*)(y_t + (((size_t)(b * Nc + n0 + r)) << 7) + cl * 8) =
        *(const bf16x8*)(Ys + r * 128 + cl * 8);
  }
}

// ---------------------------------------------------------------------------
// Kernel 4: W_y = conv1x1(y, W_w)+W_b; channel LayerNorm; +x residual
// y_t is [B][N][128] bf16. grid (N/16, B), block 256.
// ---------------------------------------------------------------------------
__global__ __launch_bounds__(256) void k_wconv_ln(
    const unsigned short* __restrict__ y_t, const float* __restrict__ ww,
    const float* __restrict__ wbias, const float* __restrict__ gamma,
    const float* __restrict__ beta, const float* __restrict__ x,
    float* __restrict__ out) {
  __shared__ float ys[128 * 17];   // [ci][p], stride 17 (4-way max on writes)
  __shared__ float red[2][4][16];
  const int n0 = blockIdx.x * 16;
  const int b  = blockIdx.y;
  const int t  = threadIdx.x;
  {
    int p = t >> 4, cl = t & 15;
    bf16x8 v = *(const bf16x8*)(
        y_t + (((size_t)(b * Nc + n0 + p)) << 7) + cl * 8);
    const unsigned short* vb = (const unsigned short*)&v;
#pragma unroll
    for (int j = 0; j < 8; ++j) ys[(cl * 8 + j) * 17 + p] = bf2f(vb[j]);
  }
  __syncthreads();
  float acc0[16], acc1[16];
  const float b0 = wbias[t], b1 = wbias[t + 256];
#pragma unroll
  for (int p = 0; p < 16; ++p) { acc0[p] = b0; acc1[p] = b1; }
  const float4* w0p = (const float4*)(ww + (size_t)t * CIc);
  const float4* w1p = (const float4*)(ww + (size_t)(t + 256) * CIc);
  for (int c4 = 0; c4 < 32; ++c4) {
    float4 w0 = w0p[c4], w1 = w1p[c4];
    const float* yr = &ys[c4 * 4 * 17];
#pragma unroll
    for (int p = 0; p < 16; ++p) {
      float a = yr[p], bb = yr[17 + p], cc = yr[34 + p], dd = yr[51 + p];
      acc0[p] += w0.x * a + w0.y * bb + w0.z * cc + w0.w * dd;
      acc1[p] += w1.x * a + w1.y * bb + w1.z * cc + w1.w * dd;
    }
  }
  const int lane = t & 63, wv = t >> 6;
#pragma unroll
  for (int p = 0; p < 16; ++p) {
    float sv = acc0[p] + acc1[p];
    float qv = acc0[p] * acc0[p] + acc1[p] * acc1[p];
#pragma unroll
    for (int off = 32; off; off >>= 1) {
      sv += __shfl_xor(sv, off);
      qv += __shfl_xor(qv, off);
    }
    if (lane == 0) { red[0][wv][p] = sv; red[1][wv][p] = qv; }
  }
  __syncthreads();
  const float ga0 = gamma[t], be0 = beta[t], ga1 = gamma[t + 256], be1 = beta[t + 256];
  const size_t base0 = (size_t)b * Cc * Nc + (size_t)t * Nc + n0;
  const size_t base1 = (size_t)b * Cc * Nc + (size_t)(t + 256) * Nc + n0;
#pragma unroll
  for (int p = 0; p < 16; ++p) {
    float s = red[0][0][p] + red[0][1][p] + red[0][2][p] + red[0][3][p];
    float q = red[1][0][p] + red[1][1][p] + red[1][2][p] + red[1][3][p];
    float mu  = s * (1.f / 512.f);
    float var = q * (1.f / 512.f) - mu * mu;
    float rs  = rsqrtf(var + 1e-5f);
    out[base0 + p] = (acc0[p] - mu) * rs * ga0 + be0 + x[base0 + p];
    out[base1 + p] = (acc1[p] - mu) * rs * ga1 + be1 + x[base1 + p];
  }
}

// ---------------------------------------------------------------------------
extern "C" void kernel_launch(void* const* d_in, const int* in_sizes, int n_in,
                              void* d_out, int out_size, void* d_ws, size_t ws_size,
                              hipStream_t stream) {
  const float* x       = (const float*)d_in[0];
  const float* g_w     = (const float*)d_in[1];
  const float* g_b     = (const float*)d_in[2];
  const float* phi_w   = (const float*)d_in[3];
  const float* phi_b   = (const float*)d_in[4];
  const float* theta_w = (const float*)d_in[5];
  const float* theta_b = (const float*)d_in[6];
  const float* W_w     = (const float*)d_in[7];
  const float* W_b     = (const float*)d_in[8];
  const float* ln_g    = (const float*)d_in[9];
  const float* ln_b    = (const float*)d_in[10];
  float* out = (float*)d_out;

  // ws layout (bf16): theta_t [B,N,CI] | phi_t [B,M,CI] | g [B,CI,M] | y_t [B,N,CI]
  unsigned short* theta_t = (unsigned short*)d_ws;
  unsigned short* phi_t   = theta_t + (size_t)Bc * Nc * CIc;
  unsigned short* gbuf    = phi_t + (size_t)Bc * Mc * CIc;
  unsigned short* y_t     = gbuf + (size_t)Bc * Mc * CIc;
  // total 20 MiB <= ws_size

  k_conv_theta<<<dim3(Nc / 64, Bc), dim3(64, 4), 0, stream>>>(x, theta_w, theta_b, theta_t);
  k_conv_pool_gphi<<<dim3(4, 32, Bc), dim3(32, 8), 0, stream>>>(x, g_w, g_b, phi_w, phi_b, gbuf, phi_t);
  k_attn_mfma<<<dim3(Nc / 64, Bc), dim3(256), 0, stream>>>(theta_t, phi_t, gbuf, y_t);
  k_wconv_ln<<<dim3(Nc / 16, Bc), dim3(256), 0, stream>>>(y_t, W_w, W_b, ln_g, ln_b, x, out);
}

// Round 4
// 167.333 us; speedup vs baseline: 6.2765x; 2.8119x over previous
//
#include <hip/hip_runtime.h>
#include <math.h>

// Problem constants (from reference): B=8, C=512, CI=128, H=W=64
constexpr int Cc  = 512;
constexpr int CIc = 128;
constexpr int Bc  = 8;
constexpr int Nc  = 4096;   // H*W
constexpr int Mc  = 1024;   // (H/2)*(W/2)

typedef __bf16 bf16x8 __attribute__((ext_vector_type(8)));
typedef float  f32x4  __attribute__((ext_vector_type(4)));

__device__ __forceinline__ unsigned short f2bf(float f) {
  unsigned u = __float_as_uint(f);
  u += 0x7fffu + ((u >> 16) & 1u);
  return (unsigned short)(u >> 16);
}
__device__ __forceinline__ float bf2f(unsigned short h) {
  return __uint_as_float((unsigned)h << 16);
}

// ---------------------------------------------------------------------------
// Kernel 0: weight/bias prep. wcat [384][512] bf16 (rows: 0-127 theta,
// 128-255 phi, 256-383 g), wwb [512][128] bf16, bcat [384] f32.
// ---------------------------------------------------------------------------
__global__ __launch_bounds__(256) void k_prep(
    const float* __restrict__ gw, const float* __restrict__ pw,
    const float* __restrict__ tw, const float* __restrict__ Ww,
    const float* __restrict__ gb, const float* __restrict__ pb,
    const float* __restrict__ tb,
    unsigned short* __restrict__ wcat, unsigned short* __restrict__ wwb,
    float* __restrict__ bcat) {
  int i = blockIdx.x * 256 + threadIdx.x;
  if (i < 49152) {                 // wcat: 384 rows x 128 float4
    int c = i >> 7, q = i & 127;
    const float* src = (c < 128) ? tw + (size_t)c * 512
                     : (c < 256) ? pw + (size_t)(c - 128) * 512
                                 : gw + (size_t)(c - 256) * 512;
    float4 v = *(const float4*)(src + q * 4);
    ushort4 o;
    o.x = f2bf(v.x); o.y = f2bf(v.y); o.z = f2bf(v.z); o.w = f2bf(v.w);
    *(ushort4*)(wcat + (size_t)c * 512 + q * 4) = o;
  } else if (i < 65536) {          // wwb: 512 rows x 32 float4
    int i2 = i - 49152;
    int c = i2 >> 5, q = i2 & 31;
    float4 v = *(const float4*)(Ww + (size_t)c * 128 + q * 4);
    ushort4 o;
    o.x = f2bf(v.x); o.y = f2bf(v.y); o.z = f2bf(v.z); o.w = f2bf(v.w);
    *(ushort4*)(wwb + (size_t)c * 128 + q * 4) = o;
  } else if (i < 65920) {
    int j = i - 65536;
    bcat[j] = (j < 128) ? tb[j] : (j < 256) ? pb[j - 128] : gb[j - 256];
  }
}

// ---------------------------------------------------------------------------
// Kernel 1: all three projections as one MFMA GEMM.
//   out[n][c_out] for c_out in [0,384): theta|phi|g, K=512 over x channels.
//   x [B][512][N] fp32 -> theta_t/pf/gf [B][N][128] bf16 each.
// grid (N/64, B), block 256 (4 waves x 16 n-rows). K-chunks of 64.
// ---------------------------------------------------------------------------
__global__ __launch_bounds__(256) void k_conv_all(
    const float* __restrict__ x, const unsigned short* __restrict__ wcat,
    const float* __restrict__ bcat,
    unsigned short* __restrict__ theta_t, unsigned short* __restrict__ pf,
    unsigned short* __restrict__ gf) {
  __shared__ __align__(16) char smem[57856];
  unsigned short* XT = (unsigned short*)smem;            // [64 n][68] (stride 136B)
  unsigned short* WT = (unsigned short*)(smem + 8704);   // [384 c][64], swizzled 128B rows
  unsigned short* Ys = (unsigned short*)smem;            // epilogue alias [64 n][408]
  const int b = blockIdx.y, n0 = blockIdx.x * 64;
  const int t = threadIdx.x;
  const int w = t >> 6, l = t & 63, lr = l & 15, lg = l >> 4;

  f32x4 acc[24];
#pragma unroll
  for (int tc = 0; tc < 24; ++tc) acc[tc] = (f32x4){0.f, 0.f, 0.f, 0.f};

  for (int k0 = 0; k0 < 512; k0 += 64) {
    __syncthreads();
    // stage x^T tile: rows c=k0..k0+63 (coalesced float4 along n) -> XT[n][c]
#pragma unroll
    for (int it = 0; it < 4; ++it) {
      int cc = (t >> 4) + it * 16, j = t & 15;
      float4 v = *(const float4*)&x[((size_t)b * Cc + k0 + cc) * Nc + n0 + j * 4];
      XT[(j * 4 + 0) * 68 + cc] = f2bf(v.x);
      XT[(j * 4 + 1) * 68 + cc] = f2bf(v.y);
      XT[(j * 4 + 2) * 68 + cc] = f2bf(v.z);
      XT[(j * 4 + 3) * 68 + cc] = f2bf(v.w);
    }
    // stage W tile [384][64] bf16, XOR-swizzled 128B rows
#pragma unroll
    for (int it = 0; it < 12; ++it) {
      int i = it * 256 + t;
      int r = i >> 3, j = i & 7;
      bf16x8 v = *(const bf16x8*)(wcat + (size_t)r * 512 + k0 + j * 8);
      *(bf16x8*)((char*)WT + r * 128 + ((j * 16) ^ ((r & 7) << 4))) = v;
    }
    __syncthreads();
#pragma unroll
    for (int ks = 0; ks < 2; ++ks) {
      // A frag: 8 bf16 for row n = w*16+lr, k = ks*32 + lg*8 .. +7
      const unsigned short* ap = XT + (w * 16 + lr) * 68 + lg * 8 + ks * 32;
      union { ushort4 h[2]; bf16x8 v; } ab;
      ab.h[0] = *(const ushort4*)ap;
      ab.h[1] = *(const ushort4*)(ap + 4);
#pragma unroll
      for (int tc = 0; tc < 24; ++tc) {
        int r = tc * 16 + lr;
        bf16x8 bfr = *(const bf16x8*)(
            (char*)WT + r * 128 + ((lg * 16 + ks * 64) ^ ((lr & 7) << 4)));
        acc[tc] = __builtin_amdgcn_mfma_f32_16x16x32_bf16(ab.v, bfr, acc[tc], 0, 0, 0);
      }
    }
  }
  __syncthreads();
  // bias + stage strip [64 n][384 c] bf16 (stride 408)
#pragma unroll
  for (int tc = 0; tc < 24; ++tc) {
    float bv = bcat[tc * 16 + lr];
#pragma unroll
    for (int reg = 0; reg < 4; ++reg)
      Ys[(w * 16 + lg * 4 + reg) * 408 + tc * 16 + lr] = f2bf(acc[tc][reg] + bv);
  }
  __syncthreads();
  // coalesced writes to the 3 buffers
#pragma unroll
  for (int buf = 0; buf < 3; ++buf) {
    unsigned short* dst = (buf == 0) ? theta_t : (buf == 1) ? pf : gf;
#pragma unroll
    for (int it = 0; it < 4; ++it) {
      int idx = it * 256 + t;
      int n = idx >> 4, j = idx & 15;
      bf16x8 v = *(const bf16x8*)(Ys + n * 408 + buf * 128 + j * 8);
      *(bf16x8*)(dst + (((size_t)(b * Nc + n0 + n)) << 7) + j * 8) = v;
    }
  }
}

// ---------------------------------------------------------------------------
// Kernel 2: 2x2 maxpool. pf/gf [B][N][128] -> phi_t [B][M][128], g [B][128][M].
// grid (32 h2, B), block 256. Each thread: 32 pooled pos dim via t>>3,
// 16 channels via (t&7) + half*8 (FIX: previously covered only 64 channels).
// ---------------------------------------------------------------------------
__global__ __launch_bounds__(256) void k_pool(
    const unsigned short* __restrict__ pf, const unsigned short* __restrict__ gf,
    unsigned short* __restrict__ phi_t, unsigned short* __restrict__ gbuf) {
  __shared__ unsigned short T[128 * 33];
  const int h2 = blockIdx.x, b = blockIdx.y;
  const int t = threadIdx.x;
  const int ml = t >> 3, j0 = t & 7;
  const size_t base = ((size_t)(b * Nc + h2 * 128 + 2 * ml)) << 7;
#pragma unroll
  for (int half = 0; half < 2; ++half) {
    const int j = j0 + half * 8;   // channel group 0..15 (8 ch each)
    // phi: max of 4 pixels, write [m][ci] directly
    {
      bf16x8 a = *(const bf16x8*)(pf + base + j * 8);
      bf16x8 c = *(const bf16x8*)(pf + base + 128 + j * 8);
      bf16x8 d = *(const bf16x8*)(pf + base + 64 * 128 + j * 8);
      bf16x8 e = *(const bf16x8*)(pf + base + 65 * 128 + j * 8);
      const unsigned short *pa = (const unsigned short*)&a, *pc = (const unsigned short*)&c,
                           *pd = (const unsigned short*)&d, *pe = (const unsigned short*)&e;
      unsigned short o[8];
#pragma unroll
      for (int q = 0; q < 8; ++q) {
        float m0 = fmaxf(fmaxf(bf2f(pa[q]), bf2f(pc[q])), fmaxf(bf2f(pd[q]), bf2f(pe[q])));
        o[q] = f2bf(m0);
      }
      ushort4 o0, o1;
      o0.x = o[0]; o0.y = o[1]; o0.z = o[2]; o0.w = o[3];
      o1.x = o[4]; o1.y = o[5]; o1.z = o[6]; o1.w = o[7];
      unsigned short* dp = phi_t + (((size_t)(b * Mc + h2 * 32 + ml)) << 7) + j * 8;
      *(ushort4*)dp = o0;
      *(ushort4*)(dp + 4) = o1;
    }
    // g: same max, stage into LDS transpose buffer
    {
      bf16x8 a = *(const bf16x8*)(gf + base + j * 8);
      bf16x8 c = *(const bf16x8*)(gf + base + 128 + j * 8);
      bf16x8 d = *(const bf16x8*)(gf + base + 64 * 128 + j * 8);
      bf16x8 e = *(const bf16x8*)(gf + base + 65 * 128 + j * 8);
      const unsigned short *pa = (const unsigned short*)&a, *pc = (const unsigned short*)&c,
                           *pd = (const unsigned short*)&d, *pe = (const unsigned short*)&e;
#pragma unroll
      for (int q = 0; q < 8; ++q) {
        float m0 = fmaxf(fmaxf(bf2f(pa[q]), bf2f(pc[q])), fmaxf(bf2f(pd[q]), bf2f(pe[q])));
        T[(j * 8 + q) * 33 + ml] = f2bf(m0);
      }
    }
  }
  __syncthreads();
  {
    int ci = t >> 1, half = t & 1;
    unsigned short tmp[16];
#pragma unroll
    for (int q = 0; q < 16; ++q) tmp[q] = T[ci * 33 + half * 16 + q];
    unsigned short* dst = gbuf + ((size_t)(b * CIc + ci)) * Mc + h2 * 32 + half * 16;
    *(ushort4*)(dst + 0)  = *(ushort4*)(tmp + 0);
    *(ushort4*)(dst + 4)  = *(ushort4*)(tmp + 4);
    *(ushort4*)(dst + 8)  = *(ushort4*)(tmp + 8);
    *(ushort4*)(dst + 12) = *(ushort4*)(tmp + 12);
  }
}

// ---------------------------------------------------------------------------
// Kernel 3: MFMA flash attention (unchanged from passing round 2).
// ---------------------------------------------------------------------------
__global__ __launch_bounds__(256) void k_attn_mfma(
    const unsigned short* __restrict__ theta_t,
    const unsigned short* __restrict__ phi_t,
    const unsigned short* __restrict__ gv,
    unsigned short* __restrict__ y_t) {
  __shared__ __align__(16) char Ks[64 * 256];
  __shared__ __align__(16) char Vs[128 * 128];
  __shared__ __align__(16) unsigned short Ps[4][16][72];
  const int b = blockIdx.y, n0 = blockIdx.x * 64;
  const int tid = threadIdx.x;
  const int w = tid >> 6, l = tid & 63;
  const int lr = l & 15, lg = l >> 4;

  bf16x8 qf[4];
  {
    const unsigned short* qp =
        theta_t + (((size_t)(b * Nc + n0 + w * 16 + lr)) << 7);
#pragma unroll
    for (int kk = 0; kk < 4; ++kk)
      qf[kk] = *(const bf16x8*)(qp + kk * 32 + lg * 8);
  }
  f32x4 of[8];
#pragma unroll
  for (int ct = 0; ct < 8; ++ct) of[ct] = (f32x4){0.f, 0.f, 0.f, 0.f};
  float run_m[4], run_l[4];
#pragma unroll
  for (int r = 0; r < 4; ++r) { run_m[r] = -1e30f; run_l[r] = 0.f; }

  for (int t = 0; t < Mc / 64; ++t) {
    __syncthreads();
    {
      const unsigned short* kp = phi_t + (((size_t)(b * Mc + t * 64)) << 7);
#pragma unroll
      for (int it = 0; it < 4; ++it) {
        int i = it * 256 + tid;
        int r = i >> 4, cl = i & 15;
        bf16x8 v = *(const bf16x8*)(kp + (r << 7) + cl * 8);
        *(bf16x8*)(Ks + r * 256 + ((cl * 16) ^ ((r & 7) << 4))) = v;
      }
    }
    {
      const unsigned short* vp = gv + (((size_t)b) << 17) + t * 64;
#pragma unroll
      for (int it = 0; it < 4; ++it) {
        int i = it * 256 + tid;
        int ci = i >> 3, cl = i & 7;
        bf16x8 v = *(const bf16x8*)(vp + (ci << 10) + cl * 8);
        *(bf16x8*)(Vs + ci * 128 + ((cl * 16) ^ ((ci & 7) << 4))) = v;
      }
    }
    __syncthreads();
    f32x4 sm[4];
#pragma unroll
    for (int mt = 0; mt < 4; ++mt) {
      f32x4 s = (f32x4){0.f, 0.f, 0.f, 0.f};
#pragma unroll
      for (int kk = 0; kk < 4; ++kk) {
        bf16x8 kf = *(const bf16x8*)(
            Ks + (mt * 16 + lr) * 256 + ((kk * 64 + lg * 16) ^ ((lr & 7) << 4)));
        s = __builtin_amdgcn_mfma_f32_16x16x32_bf16(qf[kk], kf, s, 0, 0, 0);
      }
      sm[mt] = s;
    }
#pragma unroll
    for (int reg = 0; reg < 4; ++reg) {
      float mx = fmaxf(fmaxf(sm[0][reg], sm[1][reg]), fmaxf(sm[2][reg], sm[3][reg]));
      mx = fmaxf(mx, __shfl_xor(mx, 1));
      mx = fmaxf(mx, __shfl_xor(mx, 2));
      mx = fmaxf(mx, __shfl_xor(mx, 4));
      mx = fmaxf(mx, __shfl_xor(mx, 8));
      float nm = fmaxf(run_m[reg], mx);
      float sc = __expf(run_m[reg] - nm);
      run_m[reg] = nm;
      float rs = 0.f;
#pragma unroll
      for (int mt = 0; mt < 4; ++mt) {
        float p = __expf(sm[mt][reg] - nm);
        Ps[w][lg * 4 + reg][mt * 16 + lr] = f2bf(p);
        rs += p;
      }
      rs += __shfl_xor(rs, 1);
      rs += __shfl_xor(rs, 2);
      rs += __shfl_xor(rs, 4);
      rs += __shfl_xor(rs, 8);
      run_l[reg] = run_l[reg] * sc + rs;
#pragma unroll
      for (int ct = 0; ct < 8; ++ct) of[ct][reg] *= sc;
    }
    bf16x8 pa0 = *(const bf16x8*)(&Ps[w][lr][lg * 8]);
    bf16x8 pa1 = *(const bf16x8*)(&Ps[w][lr][32 + lg * 8]);
#pragma unroll
    for (int ct = 0; ct < 8; ++ct) {
      bf16x8 vf0 = *(const bf16x8*)(
          Vs + (ct * 16 + lr) * 128 + ((lg * 16) ^ ((lr & 7) << 4)));
      of[ct] = __builtin_amdgcn_mfma_f32_16x16x32_bf16(pa0, vf0, of[ct], 0, 0, 0);
      bf16x8 vf1 = *(const bf16x8*)(
          Vs + (ct * 16 + lr) * 128 + ((64 + lg * 16) ^ ((lr & 7) << 4)));
      of[ct] = __builtin_amdgcn_mfma_f32_16x16x32_bf16(pa1, vf1, of[ct], 0, 0, 0);
    }
  }
  float invl[4];
#pragma unroll
  for (int reg = 0; reg < 4; ++reg) invl[reg] = 1.f / run_l[reg];
  __syncthreads();
  unsigned short* Ys = (unsigned short*)Ks;
#pragma unroll
  for (int ct = 0; ct < 8; ++ct)
#pragma unroll
    for (int reg = 0; reg < 4; ++reg)
      Ys[(w * 16 + lg * 4 + reg) * 128 + ct * 16 + lr] =
          f2bf(of[ct][reg] * invl[reg]);
  __syncthreads();
#pragma unroll
  for (int it = 0; it < 4; ++it) {
    int i = it * 256 + tid;
    int r = i >> 4, cl = i & 15;
    *(bf16x8*)(y_t + (((size_t)(b * Nc + n0 + r)) << 7) + cl * 8) =
        *(const bf16x8*)(Ys + r * 128 + cl * 8);
  }
}

// ---------------------------------------------------------------------------
// Kernel 4: MFMA W-conv + channels-first LayerNorm + residual.
//   y_t [B][N][128] bf16, wwb [512][128] bf16 -> out [B][512][N] fp32.
// grid (N/64, B), block 256 (4 waves x 16 n). Each wave: 16 n x all 512 c.
// ---------------------------------------------------------------------------
__global__ __launch_bounds__(256) void k_wconv_mfma(
    const unsigned short* __restrict__ y_t, const unsigned short* __restrict__ wwb,
    const float* __restrict__ wbias, const float* __restrict__ gamma,
    const float* __restrict__ beta, const float* __restrict__ x,
    float* __restrict__ out) {
  __shared__ __align__(16) char smem[36864];
  unsigned short* WTs = (unsigned short*)smem;  // [128][128] swizzled 256B rows
  float* Ys = (float*)smem;                     // epilogue alias [128 c][72 n]
  const int b = blockIdx.y, n0 = blockIdx.x * 64;
  const int t = threadIdx.x;
  const int w = t >> 6, l = t & 63, lr = l & 15, lg = l >> 4;

  bf16x8 qf[4];
  {
    const unsigned short* qp = y_t + (((size_t)(b * Nc + n0 + w * 16 + lr)) << 7);
#pragma unroll
    for (int kk = 0; kk < 4; ++kk)
      qf[kk] = *(const bf16x8*)(qp + kk * 32 + lg * 8);
  }
  f32x4 acc[32];
#pragma unroll
  for (int i = 0; i < 32; ++i) acc[i] = (f32x4){0.f, 0.f, 0.f, 0.f};

#pragma unroll
  for (int cc = 0; cc < 4; ++cc) {
    __syncthreads();
#pragma unroll
    for (int it = 0; it < 8; ++it) {
      int i = it * 256 + t;
      int r = i >> 4, j = i & 15;
      bf16x8 v = *(const bf16x8*)(wwb + (((size_t)(cc * 128 + r)) << 7) + j * 8);
      *(bf16x8*)((char*)WTs + r * 256 + ((j * 16) ^ ((r & 7) << 4))) = v;
    }
    __syncthreads();
#pragma unroll
    for (int tc = 0; tc < 8; ++tc) {
      f32x4 a = acc[cc * 8 + tc];
      int r = tc * 16 + lr;
#pragma unroll
      for (int kk = 0; kk < 4; ++kk) {
        bf16x8 kf = *(const bf16x8*)(
            (char*)WTs + r * 256 + ((kk * 64 + lg * 16) ^ ((lr & 7) << 4)));
        a = __builtin_amdgcn_mfma_f32_16x16x32_bf16(qf[kk], kf, a, 0, 0, 0);
      }
      acc[cc * 8 + tc] = a;
    }
  }
  float s[4] = {0.f, 0.f, 0.f, 0.f}, q[4] = {0.f, 0.f, 0.f, 0.f};
#pragma unroll
  for (int cc = 0; cc < 4; ++cc)
#pragma unroll
    for (int tc = 0; tc < 8; ++tc) {
      float wb = wbias[cc * 128 + tc * 16 + lr];
      f32x4 a = acc[cc * 8 + tc];
#pragma unroll
      for (int reg = 0; reg < 4; ++reg) {
        a[reg] += wb;
        s[reg] += a[reg];
        q[reg] += a[reg] * a[reg];
      }
      acc[cc * 8 + tc] = a;
    }
  float mu[4], rs[4];
#pragma unroll
  for (int reg = 0; reg < 4; ++reg) {
    float sv = s[reg], qv = q[reg];
    sv += __shfl_xor(sv, 1); qv += __shfl_xor(qv, 1);
    sv += __shfl_xor(sv, 2); qv += __shfl_xor(qv, 2);
    sv += __shfl_xor(sv, 4); qv += __shfl_xor(qv, 4);
    sv += __shfl_xor(sv, 8); qv += __shfl_xor(qv, 8);
    mu[reg] = sv * (1.f / 512.f);
    float var = qv * (1.f / 512.f) - mu[reg] * mu[reg];
    rs[reg] = rsqrtf(var + 1e-5f);
  }
#pragma unroll
  for (int cc = 0; cc < 4; ++cc) {
    __syncthreads();
#pragma unroll
    for (int tc = 0; tc < 8; ++tc) {
      int c = cc * 128 + tc * 16 + lr;
      float ga = gamma[c], be = beta[c];
#pragma unroll
      for (int reg = 0; reg < 4; ++reg)
        Ys[(tc * 16 + lr) * 72 + w * 16 + lg * 4 + reg] =
            (acc[cc * 8 + tc][reg] - mu[reg]) * rs[reg] * ga + be;
    }
    __syncthreads();
#pragma unroll
    for (int it = 0; it < 8; ++it) {
      int idx = it * 256 + t;
      int r = idx >> 4, j = idx & 15;
      float4 v = *(const float4*)&Ys[r * 72 + j * 4];
      size_t gaddr = ((size_t)b * Cc + cc * 128 + r) * Nc + n0 + j * 4;
      float4 xv = *(const float4*)&x[gaddr];
      float4 o;
      o.x = v.x + xv.x; o.y = v.y + xv.y; o.z = v.z + xv.z; o.w = v.w + xv.w;
      *(float4*)&out[gaddr] = o;
    }
  }
}

// ---------------------------------------------------------------------------
extern "C" void kernel_launch(void* const* d_in, const int* in_sizes, int n_in,
                              void* d_out, int out_size, void* d_ws, size_t ws_size,
                              hipStream_t stream) {
  const float* x       = (const float*)d_in[0];
  const float* g_w     = (const float*)d_in[1];
  const float* g_b     = (const float*)d_in[2];
  const float* phi_w   = (const float*)d_in[3];
  const float* phi_b   = (const float*)d_in[4];
  const float* theta_w = (const float*)d_in[5];
  const float* theta_b = (const float*)d_in[6];
  const float* W_w     = (const float*)d_in[7];
  const float* W_b     = (const float*)d_in[8];
  const float* ln_g    = (const float*)d_in[9];
  const float* ln_b    = (const float*)d_in[10];
  float* out = (float*)d_out;

  unsigned short* theta_t = (unsigned short*)d_ws;
  unsigned short* pf      = theta_t + (size_t)Bc * Nc * CIc;
  unsigned short* gf      = pf + (size_t)Bc * Nc * CIc;
  unsigned short* y_t     = gf + (size_t)Bc * Nc * CIc;
  unsigned short* phi_t   = y_t + (size_t)Bc * Nc * CIc;
  unsigned short* gbuf    = phi_t + (size_t)Bc * Mc * CIc;
  unsigned short* wcat    = gbuf + (size_t)Bc * Mc * CIc;
  unsigned short* wwb     = wcat + (size_t)384 * 512;
  float*          bcat    = (float*)(wwb + (size_t)512 * 128);

  k_prep<<<dim3(258), dim3(256), 0, stream>>>(
      g_w, phi_w, theta_w, W_w, g_b, phi_b, theta_b, wcat, wwb, bcat);
  k_conv_all<<<dim3(Nc / 64, Bc), dim3(256), 0, stream>>>(
      x, wcat, bcat, theta_t, pf, gf);
  k_pool<<<dim3(32, Bc), dim3(256), 0, stream>>>(pf, gf, phi_t, gbuf);
  k_attn_mfma<<<dim3(Nc / 64, Bc), dim3(256), 0, stream>>>(
      theta_t, phi_t, gbuf, y_t);
  k_wconv_mfma<<<dim3(Nc / 64, Bc), dim3(256), 0, stream>>>(
      y_t, wwb, W_b, ln_g, ln_b, x, out);
}

// Round 5
// 138.571 us; speedup vs baseline: 7.5793x; 1.2076x over previous
//
#include <hip/hip_runtime.h>
#include <math.h>

// Problem constants (from reference): B=8, C=512, CI=128, H=W=64
constexpr int Cc  = 512;
constexpr int CIc = 128;
constexpr int Bc  = 8;
constexpr int Nc  = 4096;   // H*W
constexpr int Mc  = 1024;   // (H/2)*(W/2)

typedef __bf16 bf16x8 __attribute__((ext_vector_type(8)));
typedef float  f32x4  __attribute__((ext_vector_type(4)));

__device__ __forceinline__ unsigned short f2bf(float f) {
  unsigned u = __float_as_uint(f);
  u += 0x7fffu + ((u >> 16) & 1u);
  return (unsigned short)(u >> 16);
}
__device__ __forceinline__ float bf2f(unsigned short h) {
  return __uint_as_float((unsigned)h << 16);
}

// async global->LDS DMA, 16B per lane; LDS dest = wave-uniform base + lane*16
__device__ __forceinline__ void gload16(const void* g, void* lds) {
  __builtin_amdgcn_global_load_lds(
      (const __attribute__((address_space(1))) unsigned int*)g,
      (__attribute__((address_space(3))) unsigned int*)lds, 16, 0, 0);
}

// ---------------------------------------------------------------------------
// Kernel 0: weight/bias prep. wcat [384][512] bf16 (rows: 0-127 theta,
// 128-255 phi, 256-383 g), wwb [512][128] bf16, bcat [384] f32.
// ---------------------------------------------------------------------------
__global__ __launch_bounds__(256) void k_prep(
    const float* __restrict__ gw, const float* __restrict__ pw,
    const float* __restrict__ tw, const float* __restrict__ Ww,
    const float* __restrict__ gb, const float* __restrict__ pb,
    const float* __restrict__ tb,
    unsigned short* __restrict__ wcat, unsigned short* __restrict__ wwb,
    float* __restrict__ bcat) {
  int i = blockIdx.x * 256 + threadIdx.x;
  if (i < 49152) {                 // wcat: 384 rows x 128 float4
    int c = i >> 7, q = i & 127;
    const float* src = (c < 128) ? tw + (size_t)c * 512
                     : (c < 256) ? pw + (size_t)(c - 128) * 512
                                 : gw + (size_t)(c - 256) * 512;
    float4 v = *(const float4*)(src + q * 4);
    ushort4 o;
    o.x = f2bf(v.x); o.y = f2bf(v.y); o.z = f2bf(v.z); o.w = f2bf(v.w);
    *(ushort4*)(wcat + (size_t)c * 512 + q * 4) = o;
  } else if (i < 65536) {          // wwb: 512 rows x 32 float4
    int i2 = i - 49152;
    int c = i2 >> 5, q = i2 & 31;
    float4 v = *(const float4*)(Ww + (size_t)c * 128 + q * 4);
    ushort4 o;
    o.x = f2bf(v.x); o.y = f2bf(v.y); o.z = f2bf(v.z); o.w = f2bf(v.w);
    *(ushort4*)(wwb + (size_t)c * 128 + q * 4) = o;
  } else if (i < 65920) {
    int j = i - 65536;
    bcat[j] = (j < 128) ? tb[j] : (j < 256) ? pb[j - 128] : gb[j - 256];
  }
}

// ---------------------------------------------------------------------------
// Kernel 1: all three projections as one MFMA GEMM.
//   out[n][c_out] for c_out in [0,384): theta|phi|g, K=512 over x channels.
//   x [B][512][N] fp32 -> theta_t/pf/gf [B][N][128] bf16 each.
// grid (N/64, B), block 256 (4 waves x 16 n-rows). K-chunks of 64.
// ---------------------------------------------------------------------------
__global__ __launch_bounds__(256) void k_conv_all(
    const float* __restrict__ x, const unsigned short* __restrict__ wcat,
    const float* __restrict__ bcat,
    unsigned short* __restrict__ theta_t, unsigned short* __restrict__ pf,
    unsigned short* __restrict__ gf) {
  __shared__ __align__(16) char smem[57856];
  unsigned short* XT = (unsigned short*)smem;            // [64 n][68] (stride 136B)
  unsigned short* WT = (unsigned short*)(smem + 8704);   // [384 c][64], swizzled 128B rows
  unsigned short* Ys = (unsigned short*)smem;            // epilogue alias [64 n][408]
  const int b = blockIdx.y, n0 = blockIdx.x * 64;
  const int t = threadIdx.x;
  const int w = t >> 6, l = t & 63, lr = l & 15, lg = l >> 4;

  f32x4 acc[24];
#pragma unroll
  for (int tc = 0; tc < 24; ++tc) acc[tc] = (f32x4){0.f, 0.f, 0.f, 0.f};

  for (int k0 = 0; k0 < 512; k0 += 64) {
    __syncthreads();
    // stage x^T tile: rows c=k0..k0+63 (coalesced float4 along n) -> XT[n][c]
#pragma unroll
    for (int it = 0; it < 4; ++it) {
      int cc = (t >> 4) + it * 16, j = t & 15;
      float4 v = *(const float4*)&x[((size_t)b * Cc + k0 + cc) * Nc + n0 + j * 4];
      XT[(j * 4 + 0) * 68 + cc] = f2bf(v.x);
      XT[(j * 4 + 1) * 68 + cc] = f2bf(v.y);
      XT[(j * 4 + 2) * 68 + cc] = f2bf(v.z);
      XT[(j * 4 + 3) * 68 + cc] = f2bf(v.w);
    }
    // stage W tile [384][64] bf16, XOR-swizzled 128B rows
#pragma unroll
    for (int it = 0; it < 12; ++it) {
      int i = it * 256 + t;
      int r = i >> 3, j = i & 7;
      bf16x8 v = *(const bf16x8*)(wcat + (size_t)r * 512 + k0 + j * 8);
      *(bf16x8*)((char*)WT + r * 128 + ((j * 16) ^ ((r & 7) << 4))) = v;
    }
    __syncthreads();
#pragma unroll
    for (int ks = 0; ks < 2; ++ks) {
      // A frag: 8 bf16 for row n = w*16+lr, k = ks*32 + lg*8 .. +7
      const unsigned short* ap = XT + (w * 16 + lr) * 68 + lg * 8 + ks * 32;
      union { ushort4 h[2]; bf16x8 v; } ab;
      ab.h[0] = *(const ushort4*)ap;
      ab.h[1] = *(const ushort4*)(ap + 4);
#pragma unroll
      for (int tc = 0; tc < 24; ++tc) {
        int r = tc * 16 + lr;
        bf16x8 bfr = *(const bf16x8*)(
            (char*)WT + r * 128 + ((lg * 16 + ks * 64) ^ ((lr & 7) << 4)));
        acc[tc] = __builtin_amdgcn_mfma_f32_16x16x32_bf16(ab.v, bfr, acc[tc], 0, 0, 0);
      }
    }
  }
  __syncthreads();
  // bias + stage strip [64 n][384 c] bf16 (stride 408)
#pragma unroll
  for (int tc = 0; tc < 24; ++tc) {
    float bv = bcat[tc * 16 + lr];
#pragma unroll
    for (int reg = 0; reg < 4; ++reg)
      Ys[(w * 16 + lg * 4 + reg) * 408 + tc * 16 + lr] = f2bf(acc[tc][reg] + bv);
  }
  __syncthreads();
  // coalesced writes to the 3 buffers
#pragma unroll
  for (int buf = 0; buf < 3; ++buf) {
    unsigned short* dst = (buf == 0) ? theta_t : (buf == 1) ? pf : gf;
#pragma unroll
    for (int it = 0; it < 4; ++it) {
      int idx = it * 256 + t;
      int n = idx >> 4, j = idx & 15;
      bf16x8 v = *(const bf16x8*)(Ys + n * 408 + buf * 128 + j * 8);
      *(bf16x8*)(dst + (((size_t)(b * Nc + n0 + n)) << 7) + j * 8) = v;
    }
  }
}

// ---------------------------------------------------------------------------
// Kernel 2: 2x2 maxpool. pf/gf [B][N][128] -> phi_t [B][M][128], g [B][128][M].
// grid (32 h2, B), block 256.
// ---------------------------------------------------------------------------
__global__ __launch_bounds__(256) void k_pool(
    const unsigned short* __restrict__ pf, const unsigned short* __restrict__ gf,
    unsigned short* __restrict__ phi_t, unsigned short* __restrict__ gbuf) {
  __shared__ unsigned short T[128 * 33];
  const int h2 = blockIdx.x, b = blockIdx.y;
  const int t = threadIdx.x;
  const int ml = t >> 3, j0 = t & 7;
  const size_t base = ((size_t)(b * Nc + h2 * 128 + 2 * ml)) << 7;
#pragma unroll
  for (int half = 0; half < 2; ++half) {
    const int j = j0 + half * 8;   // channel group 0..15 (8 ch each)
    // phi: max of 4 pixels, write [m][ci] directly
    {
      bf16x8 a = *(const bf16x8*)(pf + base + j * 8);
      bf16x8 c = *(const bf16x8*)(pf + base + 128 + j * 8);
      bf16x8 d = *(const bf16x8*)(pf + base + 64 * 128 + j * 8);
      bf16x8 e = *(const bf16x8*)(pf + base + 65 * 128 + j * 8);
      const unsigned short *pa = (const unsigned short*)&a, *pc = (const unsigned short*)&c,
                           *pd = (const unsigned short*)&d, *pe = (const unsigned short*)&e;
      unsigned short o[8];
#pragma unroll
      for (int q = 0; q < 8; ++q) {
        float m0 = fmaxf(fmaxf(bf2f(pa[q]), bf2f(pc[q])), fmaxf(bf2f(pd[q]), bf2f(pe[q])));
        o[q] = f2bf(m0);
      }
      ushort4 o0, o1;
      o0.x = o[0]; o0.y = o[1]; o0.z = o[2]; o0.w = o[3];
      o1.x = o[4]; o1.y = o[5]; o1.z = o[6]; o1.w = o[7];
      unsigned short* dp = phi_t + (((size_t)(b * Mc + h2 * 32 + ml)) << 7) + j * 8;
      *(ushort4*)dp = o0;
      *(ushort4*)(dp + 4) = o1;
    }
    // g: same max, stage into LDS transpose buffer
    {
      bf16x8 a = *(const bf16x8*)(gf + base + j * 8);
      bf16x8 c = *(const bf16x8*)(gf + base + 128 + j * 8);
      bf16x8 d = *(const bf16x8*)(gf + base + 64 * 128 + j * 8);
      bf16x8 e = *(const bf16x8*)(gf + base + 65 * 128 + j * 8);
      const unsigned short *pa = (const unsigned short*)&a, *pc = (const unsigned short*)&c,
                           *pd = (const unsigned short*)&d, *pe = (const unsigned short*)&e;
#pragma unroll
      for (int q = 0; q < 8; ++q) {
        float m0 = fmaxf(fmaxf(bf2f(pa[q]), bf2f(pc[q])), fmaxf(bf2f(pd[q]), bf2f(pe[q])));
        T[(j * 8 + q) * 33 + ml] = f2bf(m0);
      }
    }
  }
  __syncthreads();
  {
    int ci = t >> 1, half = t & 1;
    unsigned short tmp[16];
#pragma unroll
    for (int q = 0; q < 16; ++q) tmp[q] = T[ci * 33 + half * 16 + q];
    unsigned short* dst = gbuf + ((size_t)(b * CIc + ci)) * Mc + h2 * 32 + half * 16;
    *(ushort4*)(dst + 0)  = *(ushort4*)(tmp + 0);
    *(ushort4*)(dst + 4)  = *(ushort4*)(tmp + 4);
    *(ushort4*)(dst + 8)  = *(ushort4*)(tmp + 8);
    *(ushort4*)(dst + 12) = *(ushort4*)(tmp + 12);
  }
}

// ---------------------------------------------------------------------------
// Kernel 3: MFMA flash attention, double-buffered async staging.
//   theta_t [B][N][128] (Q), phi_t [B][M][128] (K), gv [B][128][M] (V)
//   -> y_t [B][N][128] bf16.
// grid (N/64, B), block 256 (4 waves x 16 q-rows). KV tiles of 64.
// Staging: global_load_lds with PRE-SWIZZLED per-lane source addresses
// (linear LDS dest + inverse-XOR source == swizzled LDS; XOR is involutive,
// so the MFMA-side swizzled reads are unchanged from the verified version).
// One s_barrier per tile; next-tile DMA flies under current-tile compute.
// ---------------------------------------------------------------------------
__global__ __launch_bounds__(256) void k_attn_mfma(
    const unsigned short* __restrict__ theta_t,
    const unsigned short* __restrict__ phi_t,
    const unsigned short* __restrict__ gv,
    unsigned short* __restrict__ y_t) {
  __shared__ __align__(16) char Kb[2][16384];   // [64 m][256B] swizzled
  __shared__ __align__(16) char Vb[2][16384];   // [128 ci][128B] swizzled
  __shared__ __align__(16) unsigned short Ps[4][16][72];  // per-wave P tile
  const int b = blockIdx.y, n0 = blockIdx.x * 64;
  const int tid = threadIdx.x;
  const int w = tid >> 6, l = tid & 63;
  const int lr = l & 15, lg = l >> 4;

  // --- per-lane pre-swizzled staging source offsets (bytes) ---
  // K instr i: LDS region (w*4+i)*1KB = rows [w*16+i*4, +4), lane covers
  // row w*16+i*4+(l>>4), chunk (l&15)*16; source chunk = chunk ^ ((row&7)<<4).
  const int krow_l = l >> 4, kchunk = (l & 15) * 16;
  const int vrow_l = l >> 3, vchunk = (l & 7) * 16;
  int koff[4], voff[4];
#pragma unroll
  for (int i = 0; i < 4; ++i) {
    int kr = w * 16 + i * 4 + krow_l;
    koff[i] = kr * 256 + (kchunk ^ ((kr & 7) << 4));
    int vr = w * 32 + i * 8 + vrow_l;
    voff[i] = vr * 2048 + (vchunk ^ ((vr & 7) << 4));
  }
  const char* kbase = (const char*)(phi_t + (((size_t)(b * Mc)) << 7));
  const char* vbase = (const char*)(gv + (((size_t)b) << 17));

  auto stage = [&](int buf, int t) {
#pragma unroll
    for (int i = 0; i < 4; ++i)
      gload16(kbase + t * 16384 + koff[i], &Kb[buf][(w * 4 + i) * 1024]);
#pragma unroll
    for (int i = 0; i < 4; ++i)
      gload16(vbase + t * 128 + voff[i], &Vb[buf][(w * 4 + i) * 1024]);
  };

  // Q fragments: rows n0 + w*16 + lr, k-tiles of 32 channels
  bf16x8 qf[4];
  {
    const unsigned short* qp =
        theta_t + (((size_t)(b * Nc + n0 + w * 16 + lr)) << 7);
#pragma unroll
    for (int kk = 0; kk < 4; ++kk)
      qf[kk] = *(const bf16x8*)(qp + kk * 32 + lg * 8);
  }
  f32x4 of[8];
#pragma unroll
  for (int ct = 0; ct < 8; ++ct) of[ct] = (f32x4){0.f, 0.f, 0.f, 0.f};
  float run_m[4], run_l[4];
#pragma unroll
  for (int r = 0; r < 4; ++r) { run_m[r] = -1e30f; run_l[r] = 0.f; }

  // prologue: stage tile 0, drain, align
  stage(0, 0);
  asm volatile("s_waitcnt vmcnt(0)" ::: "memory");
  __builtin_amdgcn_s_barrier();

  for (int t = 0; t < Mc / 64; ++t) {
    const int cur = t & 1;
    // issue next-tile DMA (other buffer; everyone is done reading it)
    if (t + 1 < Mc / 64) stage(cur ^ 1, t + 1);
    const char* Ks = Kb[cur];
    const char* Vs = Vb[cur];
    // QK^T: S strip [16 n x 64 m] per wave
    f32x4 sm[4];
    __builtin_amdgcn_s_setprio(1);
#pragma unroll
    for (int mt = 0; mt < 4; ++mt) {
      f32x4 s = (f32x4){0.f, 0.f, 0.f, 0.f};
#pragma unroll
      for (int kk = 0; kk < 4; ++kk) {
        bf16x8 kf = *(const bf16x8*)(
            Ks + (mt * 16 + lr) * 256 + ((kk * 64 + lg * 16) ^ ((lr & 7) << 4)));
        s = __builtin_amdgcn_mfma_f32_16x16x32_bf16(qf[kk], kf, s, 0, 0, 0);
      }
      sm[mt] = s;
    }
    __builtin_amdgcn_s_setprio(0);
    // online softmax (rows 4*lg+reg live in the 16 lanes of group lg)
#pragma unroll
    for (int reg = 0; reg < 4; ++reg) {
      float mx = fmaxf(fmaxf(sm[0][reg], sm[1][reg]), fmaxf(sm[2][reg], sm[3][reg]));
      mx = fmaxf(mx, __shfl_xor(mx, 1));
      mx = fmaxf(mx, __shfl_xor(mx, 2));
      mx = fmaxf(mx, __shfl_xor(mx, 4));
      mx = fmaxf(mx, __shfl_xor(mx, 8));
      float nm = fmaxf(run_m[reg], mx);
      float sc = __expf(run_m[reg] - nm);
      run_m[reg] = nm;
      float rs = 0.f;
#pragma unroll
      for (int mt = 0; mt < 4; ++mt) {
        float p = __expf(sm[mt][reg] - nm);
        Ps[w][lg * 4 + reg][mt * 16 + lr] = f2bf(p);
        rs += p;
      }
      rs += __shfl_xor(rs, 1);
      rs += __shfl_xor(rs, 2);
      rs += __shfl_xor(rs, 4);
      rs += __shfl_xor(rs, 8);
      run_l[reg] = run_l[reg] * sc + rs;
#pragma unroll
      for (int ct = 0; ct < 8; ++ct) of[ct][reg] *= sc;
    }
    // PV: O strip [16 n x 128 ci] per wave (Ps is wave-private: no barrier)
    bf16x8 pa0 = *(const bf16x8*)(&Ps[w][lr][lg * 8]);
    bf16x8 pa1 = *(const bf16x8*)(&Ps[w][lr][32 + lg * 8]);
    __builtin_amdgcn_s_setprio(1);
#pragma unroll
    for (int ct = 0; ct < 8; ++ct) {
      bf16x8 vf0 = *(const bf16x8*)(
          Vs + (ct * 16 + lr) * 128 + ((lg * 16) ^ ((lr & 7) << 4)));
      of[ct] = __builtin_amdgcn_mfma_f32_16x16x32_bf16(pa0, vf0, of[ct], 0, 0, 0);
      bf16x8 vf1 = *(const bf16x8*)(
          Vs + (ct * 16 + lr) * 128 + ((64 + lg * 16) ^ ((lr & 7) << 4)));
      of[ct] = __builtin_amdgcn_mfma_f32_16x16x32_bf16(pa1, vf1, of[ct], 0, 0, 0);
    }
    __builtin_amdgcn_s_setprio(0);
    // next-tile DMA landed by now (covered by compute); align all waves
    asm volatile("s_waitcnt vmcnt(0)" ::: "memory");
    __builtin_amdgcn_s_barrier();
  }
  // epilogue: normalize, stage strip in LDS (reuse Kb), coalesced bf16 write
  float invl[4];
#pragma unroll
  for (int reg = 0; reg < 4; ++reg) invl[reg] = 1.f / run_l[reg];
  unsigned short* Ys = (unsigned short*)Kb;
#pragma unroll
  for (int ct = 0; ct < 8; ++ct)
#pragma unroll
    for (int reg = 0; reg < 4; ++reg)
      Ys[(w * 16 + lg * 4 + reg) * 128 + ct * 16 + lr] =
          f2bf(of[ct][reg] * invl[reg]);
  __syncthreads();
#pragma unroll
  for (int it = 0; it < 4; ++it) {
    int i = it * 256 + tid;
    int r = i >> 4, cl = i & 15;
    *(bf16x8*)(y_t + (((size_t)(b * Nc + n0 + r)) << 7) + cl * 8) =
        *(const bf16x8*)(Ys + r * 128 + cl * 8);
  }
}

// ---------------------------------------------------------------------------
// Kernel 4: MFMA W-conv + channels-first LayerNorm + residual.
//   y_t [B][N][128] bf16, wwb [512][128] bf16 -> out [B][512][N] fp32.
// grid (N/64, B), block 256 (4 waves x 16 n). Each wave: 16 n x all 512 c.
// ---------------------------------------------------------------------------
__global__ __launch_bounds__(256) void k_wconv_mfma(
    const unsigned short* __restrict__ y_t, const unsigned short* __restrict__ wwb,
    const float* __restrict__ wbias, const float* __restrict__ gamma,
    const float* __restrict__ beta, const float* __restrict__ x,
    float* __restrict__ out) {
  __shared__ __align__(16) char smem[36864];
  unsigned short* WTs = (unsigned short*)smem;  // [128][128] swizzled 256B rows
  float* Ys = (float*)smem;                     // epilogue alias [128 c][72 n]
  const int b = blockIdx.y, n0 = blockIdx.x * 64;
  const int t = threadIdx.x;
  const int w = t >> 6, l = t & 63, lr = l & 15, lg = l >> 4;

  bf16x8 qf[4];
  {
    const unsigned short* qp = y_t + (((size_t)(b * Nc + n0 + w * 16 + lr)) << 7);
#pragma unroll
    for (int kk = 0; kk < 4; ++kk)
      qf[kk] = *(const bf16x8*)(qp + kk * 32 + lg * 8);
  }
  f32x4 acc[32];
#pragma unroll
  for (int i = 0; i < 32; ++i) acc[i] = (f32x4){0.f, 0.f, 0.f, 0.f};

#pragma unroll
  for (int cc = 0; cc < 4; ++cc) {
    __syncthreads();
#pragma unroll
    for (int it = 0; it < 8; ++it) {
      int i = it * 256 + t;
      int r = i >> 4, j = i & 15;
      bf16x8 v = *(const bf16x8*)(wwb + (((size_t)(cc * 128 + r)) << 7) + j * 8);
      *(bf16x8*)((char*)WTs + r * 256 + ((j * 16) ^ ((r & 7) << 4))) = v;
    }
    __syncthreads();
#pragma unroll
    for (int tc = 0; tc < 8; ++tc) {
      f32x4 a = acc[cc * 8 + tc];
      int r = tc * 16 + lr;
#pragma unroll
      for (int kk = 0; kk < 4; ++kk) {
        bf16x8 kf = *(const bf16x8*)(
            (char*)WTs + r * 256 + ((kk * 64 + lg * 16) ^ ((lr & 7) << 4)));
        a = __builtin_amdgcn_mfma_f32_16x16x32_bf16(qf[kk], kf, a, 0, 0, 0);
      }
      acc[cc * 8 + tc] = a;
    }
  }
  float s[4] = {0.f, 0.f, 0.f, 0.f}, q[4] = {0.f, 0.f, 0.f, 0.f};
#pragma unroll
  for (int cc = 0; cc < 4; ++cc)
#pragma unroll
    for (int tc = 0; tc < 8; ++tc) {
      float wb = wbias[cc * 128 + tc * 16 + lr];
      f32x4 a = acc[cc * 8 + tc];
#pragma unroll
      for (int reg = 0; reg < 4; ++reg) {
        a[reg] += wb;
        s[reg] += a[reg];
        q[reg] += a[reg] * a[reg];
      }
      acc[cc * 8 + tc] = a;
    }
  float mu[4], rs[4];
#pragma unroll
  for (int reg = 0; reg < 4; ++reg) {
    float sv = s[reg], qv = q[reg];
    sv += __shfl_xor(sv, 1); qv += __shfl_xor(qv, 1);
    sv += __shfl_xor(sv, 2); qv += __shfl_xor(qv, 2);
    sv += __shfl_xor(sv, 4); qv += __shfl_xor(qv, 4);
    sv += __shfl_xor(sv, 8); qv += __shfl_xor(qv, 8);
    mu[reg] = sv * (1.f / 512.f);
    float var = qv * (1.f / 512.f) - mu[reg] * mu[reg];
    rs[reg] = rsqrtf(var + 1e-5f);
  }
#pragma unroll
  for (int cc = 0; cc < 4; ++cc) {
    __syncthreads();
#pragma unroll
    for (int tc = 0; tc < 8; ++tc) {
      int c = cc * 128 + tc * 16 + lr;
      float ga = gamma[c], be = beta[c];
#pragma unroll
      for (int reg = 0; reg < 4; ++reg)
        Ys[(tc * 16 + lr) * 72 + w * 16 + lg * 4 + reg] =
            (acc[cc * 8 + tc][reg] - mu[reg]) * rs[reg] * ga + be;
    }
    __syncthreads();
#pragma unroll
    for (int it = 0; it < 8; ++it) {
      int idx = it * 256 + t;
      int r = idx >> 4, j = idx & 15;
      float4 v = *(const float4*)&Ys[r * 72 + j * 4];
      size_t gaddr = ((size_t)b * Cc + cc * 128 + r) * Nc + n0 + j * 4;
      float4 xv = *(const float4*)&x[gaddr];
      float4 o;
      o.x = v.x + xv.x; o.y = v.y + xv.y; o.z = v.z + xv.z; o.w = v.w + xv.w;
      *(float4*)&out[gaddr] = o;
    }
  }
}

// ---------------------------------------------------------------------------
extern "C" void kernel_launch(void* const* d_in, const int* in_sizes, int n_in,
                              void* d_out, int out_size, void* d_ws, size_t ws_size,
                              hipStream_t stream) {
  const float* x       = (const float*)d_in[0];
  const float* g_w     = (const float*)d_in[1];
  const float* g_b     = (const float*)d_in[2];
  const float* phi_w   = (const float*)d_in[3];
  const float* phi_b   = (const float*)d_in[4];
  const float* theta_w = (const float*)d_in[5];
  const float* theta_b = (const float*)d_in[6];
  const float* W_w     = (const float*)d_in[7];
  const float* W_b     = (const float*)d_in[8];
  const float* ln_g    = (const float*)d_in[9];
  const float* ln_b    = (const float*)d_in[10];
  float* out = (float*)d_out;

  unsigned short* theta_t = (unsigned short*)d_ws;
  unsigned short* pf      = theta_t + (size_t)Bc * Nc * CIc;
  unsigned short* gf      = pf + (size_t)Bc * Nc * CIc;
  unsigned short* y_t     = gf + (size_t)Bc * Nc * CIc;
  unsigned short* phi_t   = y_t + (size_t)Bc * Nc * CIc;
  unsigned short* gbuf    = phi_t + (size_t)Bc * Mc * CIc;
  unsigned short* wcat    = gbuf + (size_t)Bc * Mc * CIc;
  unsigned short* wwb     = wcat + (size_t)384 * 512;
  float*          bcat    = (float*)(wwb + (size_t)512 * 128);

  k_prep<<<dim3(258), dim3(256), 0, stream>>>(
      g_w, phi_w, theta_w, W_w, g_b, phi_b, theta_b, wcat, wwb, bcat);
  k_conv_all<<<dim3(Nc / 64, Bc), dim3(256), 0, stream>>>(
      x, wcat, bcat, theta_t, pf, gf);
  k_pool<<<dim3(32, Bc), dim3(256), 0, stream>>>(pf, gf, phi_t, gbuf);
  k_attn_mfma<<<dim3(Nc / 64, Bc), dim3(256), 0, stream>>>(
      theta_t, phi_t, gbuf, y_t);
  k_wconv_mfma<<<dim3(Nc / 64, Bc), dim3(256), 0, stream>>>(
      y_t, wwb, W_b, ln_g, ln_b, x, out);
}

// Round 6
// 119.268 us; speedup vs baseline: 8.8059x; 1.1618x over previous
//
#include <hip/hip_runtime.h>
#include <math.h>

// Problem constants (from reference): B=8, C=512, CI=128, H=W=64
constexpr int Cc  = 512;
constexpr int CIc = 128;
constexpr int Bc  = 8;
constexpr int Nc  = 4096;   // H*W
constexpr int Mc  = 1024;   // (H/2)*(W/2)

typedef __bf16 bf16x8 __attribute__((ext_vector_type(8)));
typedef float  f32x4  __attribute__((ext_vector_type(4)));

__device__ __forceinline__ unsigned short f2bf(float f) {
  unsigned u = __float_as_uint(f);
  u += 0x7fffu + ((u >> 16) & 1u);
  return (unsigned short)(u >> 16);
}
__device__ __forceinline__ float bf2f(unsigned short h) {
  return __uint_as_float((unsigned)h << 16);
}
__device__ __forceinline__ unsigned pack2bf(float lo, float hi) {
  return (unsigned)f2bf(lo) | ((unsigned)f2bf(hi) << 16);
}

// async global->LDS DMA, 16B per lane; LDS dest = wave-uniform base + lane*16
__device__ __forceinline__ void gload16(const void* g, void* lds) {
  __builtin_amdgcn_global_load_lds(
      (const __attribute__((address_space(1))) unsigned int*)g,
      (__attribute__((address_space(3))) unsigned int*)lds, 16, 0, 0);
}

// ---------------------------------------------------------------------------
// Kernel 0: weight/bias prep. wcat [384][512] bf16 (rows: 0-127 theta,
// 128-255 phi, 256-383 g), wwb [512][128] bf16, bcat [384] f32.
// ---------------------------------------------------------------------------
__global__ __launch_bounds__(256) void k_prep(
    const float* __restrict__ gw, const float* __restrict__ pw,
    const float* __restrict__ tw, const float* __restrict__ Ww,
    const float* __restrict__ gb, const float* __restrict__ pb,
    const float* __restrict__ tb,
    unsigned short* __restrict__ wcat, unsigned short* __restrict__ wwb,
    float* __restrict__ bcat) {
  int i = blockIdx.x * 256 + threadIdx.x;
  if (i < 49152) {                 // wcat: 384 rows x 128 float4
    int c = i >> 7, q = i & 127;
    const float* src = (c < 128) ? tw + (size_t)c * 512
                     : (c < 256) ? pw + (size_t)(c - 128) * 512
                                 : gw + (size_t)(c - 256) * 512;
    float4 v = *(const float4*)(src + q * 4);
    ushort4 o;
    o.x = f2bf(v.x); o.y = f2bf(v.y); o.z = f2bf(v.z); o.w = f2bf(v.w);
    *(ushort4*)(wcat + (size_t)c * 512 + q * 4) = o;
  } else if (i < 65536) {          // wwb: 512 rows x 32 float4
    int i2 = i - 49152;
    int c = i2 >> 5, q = i2 & 31;
    float4 v = *(const float4*)(Ww + (size_t)c * 128 + q * 4);
    ushort4 o;
    o.x = f2bf(v.x); o.y = f2bf(v.y); o.z = f2bf(v.z); o.w = f2bf(v.w);
    *(ushort4*)(wwb + (size_t)c * 128 + q * 4) = o;
  } else if (i < 65920) {
    int j = i - 65536;
    bcat[j] = (j < 128) ? tb[j] : (j < 256) ? pb[j - 128] : gb[j - 256];
  }
}

// ---------------------------------------------------------------------------
// Kernel 1: all three projections as one MFMA GEMM (async/dbuf rewrite).
//   x [B][512][N] fp32, wcat [384][512] bf16 -> theta_t/pf/gf [B][N][128] bf16.
// grid (N/128, B) = 256 blocks (1/CU), 512 threads (8 waves x 16 n-rows).
// A-frags (x): per-lane dword loads direct to regs + in-reg f2bf (no LDS).
// B-tiles (W): [384][64] bf16 per K-chunk, double-buffered global_load_lds
// with pre-swizzled source; one barrier per chunk.
// ---------------------------------------------------------------------------
__global__ __launch_bounds__(512) void k_conv_all(
    const float* __restrict__ x, const unsigned short* __restrict__ wcat,
    const float* __restrict__ bcat,
    unsigned short* __restrict__ theta_t, unsigned short* __restrict__ pf,
    unsigned short* __restrict__ gf) {
  __shared__ __align__(16) char smem[98304];   // W dbuf [2][49152]; epilogue alias
  const int b = blockIdx.y, n0 = blockIdx.x * 128;
  const int t = threadIdx.x;
  const int w = t >> 6, l = t & 63, lr = l & 15, lg = l >> 4;

  // per-lane pre-swizzled W staging source offsets (bytes):
  // wave w instr i writes LDS rows [(w*6+i)*8, +8) linearly; lane covers
  // row base+(l>>3), chunk (l&7)*16; source chunk = chunk ^ ((row&7)<<4).
  const char* wsrc = (const char*)wcat;   // row stride 1024 B
  int woff[6];
#pragma unroll
  for (int i = 0; i < 6; ++i) {
    int r = (w * 6 + i) * 8 + (l >> 3);
    woff[i] = r * 1024 + (((l & 7) * 16) ^ ((r & 7) << 4));
  }

  // x base for this lane's A-row: n = n0 + w*16 + lr
  const float* xb = x + (size_t)b * Cc * Nc + n0 + w * 16 + lr;

  float xraw[16];
#define LOADX(k0_)                                                        \
  {                                                                       \
    _Pragma("unroll")                                                     \
    for (int ks = 0; ks < 2; ++ks)                                        \
      _Pragma("unroll")                                                   \
      for (int j = 0; j < 8; ++j)                                         \
        xraw[ks * 8 + j] = xb[(size_t)((k0_) + ks * 32 + lg * 8 + j) * Nc]; \
  }
#define STAGEW(buf_, k0_)                                                 \
  {                                                                       \
    char* dst_ = smem + (buf_) * 49152;                                   \
    _Pragma("unroll")                                                     \
    for (int i = 0; i < 6; ++i)                                           \
      gload16(wsrc + (size_t)(k0_) * 2 + woff[i], dst_ + (w * 6 + i) * 1024); \
  }

  f32x4 acc[24];
#pragma unroll
  for (int tc = 0; tc < 24; ++tc) acc[tc] = (f32x4){0.f, 0.f, 0.f, 0.f};

  // prologue
  LOADX(0);
  STAGEW(0, 0);
  asm volatile("s_waitcnt vmcnt(0)" ::: "memory");
  __builtin_amdgcn_s_barrier();

  for (int c = 0; c < 8; ++c) {
    const int cur = c & 1;
    // convert current chunk's x to A-frags (frees xraw for next prefetch)
    bf16x8 af[2];
#pragma unroll
    for (int ks = 0; ks < 2; ++ks) {
      union { unsigned u[4]; bf16x8 v; } ab;
#pragma unroll
      for (int q = 0; q < 4; ++q)
        ab.u[q] = pack2bf(xraw[ks * 8 + 2 * q], xraw[ks * 8 + 2 * q + 1]);
      af[ks] = ab.v;
    }
    // issue next chunk's loads (fly under MFMA below)
    if (c < 7) {
      LOADX((c + 1) * 64);
      STAGEW(cur ^ 1, (c + 1) * 64);
    }
    const char* Wb = smem + cur * 49152;
    __builtin_amdgcn_s_setprio(1);
#pragma unroll
    for (int ks = 0; ks < 2; ++ks)
#pragma unroll
      for (int tc = 0; tc < 24; ++tc) {
        int r = tc * 16 + lr;
        bf16x8 bfr = *(const bf16x8*)(
            Wb + r * 128 + ((lg * 16 + ks * 64) ^ ((lr & 7) << 4)));
        acc[tc] = __builtin_amdgcn_mfma_f32_16x16x32_bf16(af[ks], bfr, acc[tc], 0, 0, 0);
      }
    __builtin_amdgcn_s_setprio(0);
    asm volatile("s_waitcnt vmcnt(0)" ::: "memory");
    __builtin_amdgcn_s_barrier();
  }
#undef LOADX
#undef STAGEW

  // epilogue: two 64-row halves; bias + bf16 strip [64][408] in LDS, then
  // coalesced bf16x8 writes to the three buffers.
  unsigned short* Ys = (unsigned short*)smem;
#pragma unroll
  for (int h = 0; h < 2; ++h) {
    __syncthreads();
    if ((w >> 2) == h) {
      int rw = (w & 3) * 16;
#pragma unroll
      for (int tc = 0; tc < 24; ++tc) {
        float bv = bcat[tc * 16 + lr];
#pragma unroll
        for (int reg = 0; reg < 4; ++reg)
          Ys[(rw + lg * 4 + reg) * 408 + tc * 16 + lr] = f2bf(acc[tc][reg] + bv);
      }
    }
    __syncthreads();
#pragma unroll
    for (int buf = 0; buf < 3; ++buf) {
      unsigned short* dst = (buf == 0) ? theta_t : (buf == 1) ? pf : gf;
#pragma unroll
      for (int it = 0; it < 2; ++it) {
        int idx = it * 512 + t;          // 1024 = 64 rows x 16 chunks
        int n = idx >> 4, j = idx & 15;
        bf16x8 v = *(const bf16x8*)(Ys + n * 408 + buf * 128 + j * 8);
        *(bf16x8*)(dst + (((size_t)(b * Nc + n0 + h * 64 + n)) << 7) + j * 8) = v;
      }
    }
  }
}

// ---------------------------------------------------------------------------
// Kernel 2: 2x2 maxpool. pf/gf [B][N][128] -> phi_t [B][M][128], g [B][128][M].
// grid (32 h2, B), block 256.
// ---------------------------------------------------------------------------
__global__ __launch_bounds__(256) void k_pool(
    const unsigned short* __restrict__ pf, const unsigned short* __restrict__ gf,
    unsigned short* __restrict__ phi_t, unsigned short* __restrict__ gbuf) {
  __shared__ unsigned short T[128 * 33];
  const int h2 = blockIdx.x, b = blockIdx.y;
  const int t = threadIdx.x;
  const int ml = t >> 3, j0 = t & 7;
  const size_t base = ((size_t)(b * Nc + h2 * 128 + 2 * ml)) << 7;
#pragma unroll
  for (int half = 0; half < 2; ++half) {
    const int j = j0 + half * 8;   // channel group 0..15 (8 ch each)
    {
      bf16x8 a = *(const bf16x8*)(pf + base + j * 8);
      bf16x8 c = *(const bf16x8*)(pf + base + 128 + j * 8);
      bf16x8 d = *(const bf16x8*)(pf + base + 64 * 128 + j * 8);
      bf16x8 e = *(const bf16x8*)(pf + base + 65 * 128 + j * 8);
      const unsigned short *pa = (const unsigned short*)&a, *pc = (const unsigned short*)&c,
                           *pd = (const unsigned short*)&d, *pe = (const unsigned short*)&e;
      unsigned short o[8];
#pragma unroll
      for (int q = 0; q < 8; ++q) {
        float m0 = fmaxf(fmaxf(bf2f(pa[q]), bf2f(pc[q])), fmaxf(bf2f(pd[q]), bf2f(pe[q])));
        o[q] = f2bf(m0);
      }
      ushort4 o0, o1;
      o0.x = o[0]; o0.y = o[1]; o0.z = o[2]; o0.w = o[3];
      o1.x = o[4]; o1.y = o[5]; o1.z = o[6]; o1.w = o[7];
      unsigned short* dp = phi_t + (((size_t)(b * Mc + h2 * 32 + ml)) << 7) + j * 8;
      *(ushort4*)dp = o0;
      *(ushort4*)(dp + 4) = o1;
    }
    {
      bf16x8 a = *(const bf16x8*)(gf + base + j * 8);
      bf16x8 c = *(const bf16x8*)(gf + base + 128 + j * 8);
      bf16x8 d = *(const bf16x8*)(gf + base + 64 * 128 + j * 8);
      bf16x8 e = *(const bf16x8*)(gf + base + 65 * 128 + j * 8);
      const unsigned short *pa = (const unsigned short*)&a, *pc = (const unsigned short*)&c,
                           *pd = (const unsigned short*)&d, *pe = (const unsigned short*)&e;
#pragma unroll
      for (int q = 0; q < 8; ++q) {
        float m0 = fmaxf(fmaxf(bf2f(pa[q]), bf2f(pc[q])), fmaxf(bf2f(pd[q]), bf2f(pe[q])));
        T[(j * 8 + q) * 33 + ml] = f2bf(m0);
      }
    }
  }
  __syncthreads();
  {
    int ci = t >> 1, half = t & 1;
    unsigned short tmp[16];
#pragma unroll
    for (int q = 0; q < 16; ++q) tmp[q] = T[ci * 33 + half * 16 + q];
    unsigned short* dst = gbuf + ((size_t)(b * CIc + ci)) * Mc + h2 * 32 + half * 16;
    *(ushort4*)(dst + 0)  = *(ushort4*)(tmp + 0);
    *(ushort4*)(dst + 4)  = *(ushort4*)(tmp + 4);
    *(ushort4*)(dst + 8)  = *(ushort4*)(tmp + 8);
    *(ushort4*)(dst + 12) = *(ushort4*)(tmp + 12);
  }
}

// ---------------------------------------------------------------------------
// Kernel 3: MFMA flash attention, double-buffered async staging (verified R5).
// ---------------------------------------------------------------------------
__global__ __launch_bounds__(256) void k_attn_mfma(
    const unsigned short* __restrict__ theta_t,
    const unsigned short* __restrict__ phi_t,
    const unsigned short* __restrict__ gv,
    unsigned short* __restrict__ y_t) {
  __shared__ __align__(16) char Kb[2][16384];   // [64 m][256B] swizzled
  __shared__ __align__(16) char Vb[2][16384];   // [128 ci][128B] swizzled
  __shared__ __align__(16) unsigned short Ps[4][16][72];  // per-wave P tile
  const int b = blockIdx.y, n0 = blockIdx.x * 64;
  const int tid = threadIdx.x;
  const int w = tid >> 6, l = tid & 63;
  const int lr = l & 15, lg = l >> 4;

  const int krow_l = l >> 4, kchunk = (l & 15) * 16;
  const int vrow_l = l >> 3, vchunk = (l & 7) * 16;
  int koff[4], voff[4];
#pragma unroll
  for (int i = 0; i < 4; ++i) {
    int kr = w * 16 + i * 4 + krow_l;
    koff[i] = kr * 256 + (kchunk ^ ((kr & 7) << 4));
    int vr = w * 32 + i * 8 + vrow_l;
    voff[i] = vr * 2048 + (vchunk ^ ((vr & 7) << 4));
  }
  const char* kbase = (const char*)(phi_t + (((size_t)(b * Mc)) << 7));
  const char* vbase = (const char*)(gv + (((size_t)b) << 17));

  auto stage = [&](int buf, int t) {
#pragma unroll
    for (int i = 0; i < 4; ++i)
      gload16(kbase + t * 16384 + koff[i], &Kb[buf][(w * 4 + i) * 1024]);
#pragma unroll
    for (int i = 0; i < 4; ++i)
      gload16(vbase + t * 128 + voff[i], &Vb[buf][(w * 4 + i) * 1024]);
  };

  bf16x8 qf[4];
  {
    const unsigned short* qp =
        theta_t + (((size_t)(b * Nc + n0 + w * 16 + lr)) << 7);
#pragma unroll
    for (int kk = 0; kk < 4; ++kk)
      qf[kk] = *(const bf16x8*)(qp + kk * 32 + lg * 8);
  }
  f32x4 of[8];
#pragma unroll
  for (int ct = 0; ct < 8; ++ct) of[ct] = (f32x4){0.f, 0.f, 0.f, 0.f};
  float run_m[4], run_l[4];
#pragma unroll
  for (int r = 0; r < 4; ++r) { run_m[r] = -1e30f; run_l[r] = 0.f; }

  stage(0, 0);
  asm volatile("s_waitcnt vmcnt(0)" ::: "memory");
  __builtin_amdgcn_s_barrier();

  for (int t = 0; t < Mc / 64; ++t) {
    const int cur = t & 1;
    if (t + 1 < Mc / 64) stage(cur ^ 1, t + 1);
    const char* Ks = Kb[cur];
    const char* Vs = Vb[cur];
    f32x4 sm[4];
    __builtin_amdgcn_s_setprio(1);
#pragma unroll
    for (int mt = 0; mt < 4; ++mt) {
      f32x4 s = (f32x4){0.f, 0.f, 0.f, 0.f};
#pragma unroll
      for (int kk = 0; kk < 4; ++kk) {
        bf16x8 kf = *(const bf16x8*)(
            Ks + (mt * 16 + lr) * 256 + ((kk * 64 + lg * 16) ^ ((lr & 7) << 4)));
        s = __builtin_amdgcn_mfma_f32_16x16x32_bf16(qf[kk], kf, s, 0, 0, 0);
      }
      sm[mt] = s;
    }
    __builtin_amdgcn_s_setprio(0);
#pragma unroll
    for (int reg = 0; reg < 4; ++reg) {
      float mx = fmaxf(fmaxf(sm[0][reg], sm[1][reg]), fmaxf(sm[2][reg], sm[3][reg]));
      mx = fmaxf(mx, __shfl_xor(mx, 1));
      mx = fmaxf(mx, __shfl_xor(mx, 2));
      mx = fmaxf(mx, __shfl_xor(mx, 4));
      mx = fmaxf(mx, __shfl_xor(mx, 8));
      float nm = fmaxf(run_m[reg], mx);
      float sc = __expf(run_m[reg] - nm);
      run_m[reg] = nm;
      float rs = 0.f;
#pragma unroll
      for (int mt = 0; mt < 4; ++mt) {
        float p = __expf(sm[mt][reg] - nm);
        Ps[w][lg * 4 + reg][mt * 16 + lr] = f2bf(p);
        rs += p;
      }
      rs += __shfl_xor(rs, 1);
      rs += __shfl_xor(rs, 2);
      rs += __shfl_xor(rs, 4);
      rs += __shfl_xor(rs, 8);
      run_l[reg] = run_l[reg] * sc + rs;
#pragma unroll
      for (int ct = 0; ct < 8; ++ct) of[ct][reg] *= sc;
    }
    bf16x8 pa0 = *(const bf16x8*)(&Ps[w][lr][lg * 8]);
    bf16x8 pa1 = *(const bf16x8*)(&Ps[w][lr][32 + lg * 8]);
    __builtin_amdgcn_s_setprio(1);
#pragma unroll
    for (int ct = 0; ct < 8; ++ct) {
      bf16x8 vf0 = *(const bf16x8*)(
          Vs + (ct * 16 + lr) * 128 + ((lg * 16) ^ ((lr & 7) << 4)));
      of[ct] = __builtin_amdgcn_mfma_f32_16x16x32_bf16(pa0, vf0, of[ct], 0, 0, 0);
      bf16x8 vf1 = *(const bf16x8*)(
          Vs + (ct * 16 + lr) * 128 + ((64 + lg * 16) ^ ((lr & 7) << 4)));
      of[ct] = __builtin_amdgcn_mfma_f32_16x16x32_bf16(pa1, vf1, of[ct], 0, 0, 0);
    }
    __builtin_amdgcn_s_setprio(0);
    asm volatile("s_waitcnt vmcnt(0)" ::: "memory");
    __builtin_amdgcn_s_barrier();
  }
  float invl[4];
#pragma unroll
  for (int reg = 0; reg < 4; ++reg) invl[reg] = 1.f / run_l[reg];
  unsigned short* Ys = (unsigned short*)Kb;
#pragma unroll
  for (int ct = 0; ct < 8; ++ct)
#pragma unroll
    for (int reg = 0; reg < 4; ++reg)
      Ys[(w * 16 + lg * 4 + reg) * 128 + ct * 16 + lr] =
          f2bf(of[ct][reg] * invl[reg]);
  __syncthreads();
#pragma unroll
  for (int it = 0; it < 4; ++it) {
    int i = it * 256 + tid;
    int r = i >> 4, cl = i & 15;
    *(bf16x8*)(y_t + (((size_t)(b * Nc + n0 + r)) << 7) + cl * 8) =
        *(const bf16x8*)(Ys + r * 128 + cl * 8);
  }
}

// ---------------------------------------------------------------------------
// Kernel 4: MFMA W-conv + channels-first LayerNorm + residual.
//   y_t [B][N][128] bf16, wwb [512][128] bf16 -> out [B][512][N] fp32.
// grid (N/64, B), block 256 (4 waves x 16 n). Each wave: 16 n x all 512 c.
// ---------------------------------------------------------------------------
__global__ __launch_bounds__(256) void k_wconv_mfma(
    const unsigned short* __restrict__ y_t, const unsigned short* __restrict__ wwb,
    const float* __restrict__ wbias, const float* __restrict__ gamma,
    const float* __restrict__ beta, const float* __restrict__ x,
    float* __restrict__ out) {
  __shared__ __align__(16) char smem[36864];
  unsigned short* WTs = (unsigned short*)smem;  // [128][128] swizzled 256B rows
  float* Ys = (float*)smem;                     // epilogue alias [128 c][72 n]
  const int b = blockIdx.y, n0 = blockIdx.x * 64;
  const int t = threadIdx.x;
  const int w = t >> 6, l = t & 63, lr = l & 15, lg = l >> 4;

  bf16x8 qf[4];
  {
    const unsigned short* qp = y_t + (((size_t)(b * Nc + n0 + w * 16 + lr)) << 7);
#pragma unroll
    for (int kk = 0; kk < 4; ++kk)
      qf[kk] = *(const bf16x8*)(qp + kk * 32 + lg * 8);
  }
  f32x4 acc[32];
#pragma unroll
  for (int i = 0; i < 32; ++i) acc[i] = (f32x4){0.f, 0.f, 0.f, 0.f};

#pragma unroll
  for (int cc = 0; cc < 4; ++cc) {
    __syncthreads();
#pragma unroll
    for (int it = 0; it < 8; ++it) {
      int i = it * 256 + t;
      int r = i >> 4, j = i & 15;
      bf16x8 v = *(const bf16x8*)(wwb + (((size_t)(cc * 128 + r)) << 7) + j * 8);
      *(bf16x8*)((char*)WTs + r * 256 + ((j * 16) ^ ((r & 7) << 4))) = v;
    }
    __syncthreads();
#pragma unroll
    for (int tc = 0; tc < 8; ++tc) {
      f32x4 a = acc[cc * 8 + tc];
      int r = tc * 16 + lr;
#pragma unroll
      for (int kk = 0; kk < 4; ++kk) {
        bf16x8 kf = *(const bf16x8*)(
            (char*)WTs + r * 256 + ((kk * 64 + lg * 16) ^ ((lr & 7) << 4)));
        a = __builtin_amdgcn_mfma_f32_16x16x32_bf16(qf[kk], kf, a, 0, 0, 0);
      }
      acc[cc * 8 + tc] = a;
    }
  }
  float s[4] = {0.f, 0.f, 0.f, 0.f}, q[4] = {0.f, 0.f, 0.f, 0.f};
#pragma unroll
  for (int cc = 0; cc < 4; ++cc)
#pragma unroll
    for (int tc = 0; tc < 8; ++tc) {
      float wb = wbias[cc * 128 + tc * 16 + lr];
      f32x4 a = acc[cc * 8 + tc];
#pragma unroll
      for (int reg = 0; reg < 4; ++reg) {
        a[reg] += wb;
        s[reg] += a[reg];
        q[reg] += a[reg] * a[reg];
      }
      acc[cc * 8 + tc] = a;
    }
  float mu[4], rs[4];
#pragma unroll
  for (int reg = 0; reg < 4; ++reg) {
    float sv = s[reg], qv = q[reg];
    sv += __shfl_xor(sv, 1); qv += __shfl_xor(qv, 1);
    sv += __shfl_xor(sv, 2); qv += __shfl_xor(qv, 2);
    sv += __shfl_xor(sv, 4); qv += __shfl_xor(qv, 4);
    sv += __shfl_xor(sv, 8); qv += __shfl_xor(qv, 8);
    mu[reg] = sv * (1.f / 512.f);
    float var = qv * (1.f / 512.f) - mu[reg] * mu[reg];
    rs[reg] = rsqrtf(var + 1e-5f);
  }
#pragma unroll
  for (int cc = 0; cc < 4; ++cc) {
    __syncthreads();
#pragma unroll
    for (int tc = 0; tc < 8; ++tc) {
      int c = cc * 128 + tc * 16 + lr;
      float ga = gamma[c], be = beta[c];
#pragma unroll
      for (int reg = 0; reg < 4; ++reg)
        Ys[(tc * 16 + lr) * 72 + w * 16 + lg * 4 + reg] =
            (acc[cc * 8 + tc][reg] - mu[reg]) * rs[reg] * ga + be;
    }
    __syncthreads();
#pragma unroll
    for (int it = 0; it < 8; ++it) {
      int idx = it * 256 + t;
      int r = idx >> 4, j = idx & 15;
      float4 v = *(const float4*)&Ys[r * 72 + j * 4];
      size_t gaddr = ((size_t)b * Cc + cc * 128 + r) * Nc + n0 + j * 4;
      float4 xv = *(const float4*)&x[gaddr];
      float4 o;
      o.x = v.x + xv.x; o.y = v.y + xv.y; o.z = v.z + xv.z; o.w = v.w + xv.w;
      *(float4*)&out[gaddr] = o;
    }
  }
}

// ---------------------------------------------------------------------------
extern "C" void kernel_launch(void* const* d_in, const int* in_sizes, int n_in,
                              void* d_out, int out_size, void* d_ws, size_t ws_size,
                              hipStream_t stream) {
  const float* x       = (const float*)d_in[0];
  const float* g_w     = (const float*)d_in[1];
  const float* g_b     = (const float*)d_in[2];
  const float* phi_w   = (const float*)d_in[3];
  const float* phi_b   = (const float*)d_in[4];
  const float* theta_w = (const float*)d_in[5];
  const float* theta_b = (const float*)d_in[6];
  const float* W_w     = (const float*)d_in[7];
  const float* W_b     = (const float*)d_in[8];
  const float* ln_g    = (const float*)d_in[9];
  const float* ln_b    = (const float*)d_in[10];
  float* out = (float*)d_out;

  unsigned short* theta_t = (unsigned short*)d_ws;
  unsigned short* pf      = theta_t + (size_t)Bc * Nc * CIc;
  unsigned short* gf      = pf + (size_t)Bc * Nc * CIc;
  unsigned short* y_t     = gf + (size_t)Bc * Nc * CIc;
  unsigned short* phi_t   = y_t + (size_t)Bc * Nc * CIc;
  unsigned short* gbuf    = phi_t + (size_t)Bc * Mc * CIc;
  unsigned short* wcat    = gbuf + (size_t)Bc * Mc * CIc;
  unsigned short* wwb     = wcat + (size_t)384 * 512;
  float*          bcat    = (float*)(wwb + (size_t)512 * 128);

  k_prep<<<dim3(258), dim3(256), 0, stream>>>(
      g_w, phi_w, theta_w, W_w, g_b, phi_b, theta_b, wcat, wwb, bcat);
  k_conv_all<<<dim3(Nc / 128, Bc), dim3(512), 0, stream>>>(
      x, wcat, bcat, theta_t, pf, gf);
  k_pool<<<dim3(32, Bc), dim3(256), 0, stream>>>(pf, gf, phi_t, gbuf);
  k_attn_mfma<<<dim3(Nc / 64, Bc), dim3(256), 0, stream>>>(
      theta_t, phi_t, gbuf, y_t);
  k_wconv_mfma<<<dim3(Nc / 64, Bc), dim3(256), 0, stream>>>(
      y_t, wwb, W_b, ln_g, ln_b, x, out);
}

// Round 7
// 112.627 us; speedup vs baseline: 9.3252x; 1.0590x over previous
//
#include <hip/hip_runtime.h>
#include <math.h>

// Problem constants (from reference): B=8, C=512, CI=128, H=W=64
constexpr int Cc  = 512;
constexpr int CIc = 128;
constexpr int Bc  = 8;
constexpr int Nc  = 4096;   // H*W
constexpr int Mc  = 1024;   // (H/2)*(W/2)

typedef __bf16 bf16x8 __attribute__((ext_vector_type(8)));
typedef float  f32x4  __attribute__((ext_vector_type(4)));

__device__ __forceinline__ unsigned short f2bf(float f) {
  unsigned u = __float_as_uint(f);
  u += 0x7fffu + ((u >> 16) & 1u);
  return (unsigned short)(u >> 16);
}
__device__ __forceinline__ float bf2f(unsigned short h) {
  return __uint_as_float((unsigned)h << 16);
}
__device__ __forceinline__ unsigned pack2bf(float lo, float hi) {
  return (unsigned)f2bf(lo) | ((unsigned)f2bf(hi) << 16);
}

// async global->LDS DMA, 16B per lane; LDS dest = wave-uniform base + lane*16
__device__ __forceinline__ void gload16(const void* g, void* lds) {
  __builtin_amdgcn_global_load_lds(
      (const __attribute__((address_space(1))) unsigned int*)g,
      (__attribute__((address_space(3))) unsigned int*)lds, 16, 0, 0);
}

// ---------------------------------------------------------------------------
// Kernel 0: weight/bias prep. wcat [384][512] bf16 (rows: 0-127 theta,
// 128-255 phi, 256-383 g), wwb [512][128] bf16, bcat [384] f32.
// ---------------------------------------------------------------------------
__global__ __launch_bounds__(256) void k_prep(
    const float* __restrict__ gw, const float* __restrict__ pw,
    const float* __restrict__ tw, const float* __restrict__ Ww,
    const float* __restrict__ gb, const float* __restrict__ pb,
    const float* __restrict__ tb,
    unsigned short* __restrict__ wcat, unsigned short* __restrict__ wwb,
    float* __restrict__ bcat) {
  int i = blockIdx.x * 256 + threadIdx.x;
  if (i < 49152) {                 // wcat: 384 rows x 128 float4
    int c = i >> 7, q = i & 127;
    const float* src = (c < 128) ? tw + (size_t)c * 512
                     : (c < 256) ? pw + (size_t)(c - 128) * 512
                                 : gw + (size_t)(c - 256) * 512;
    float4 v = *(const float4*)(src + q * 4);
    ushort4 o;
    o.x = f2bf(v.x); o.y = f2bf(v.y); o.z = f2bf(v.z); o.w = f2bf(v.w);
    *(ushort4*)(wcat + (size_t)c * 512 + q * 4) = o;
  } else if (i < 65536) {          // wwb: 512 rows x 32 float4
    int i2 = i - 49152;
    int c = i2 >> 5, q = i2 & 31;
    float4 v = *(const float4*)(Ww + (size_t)c * 128 + q * 4);
    ushort4 o;
    o.x = f2bf(v.x); o.y = f2bf(v.y); o.z = f2bf(v.z); o.w = f2bf(v.w);
    *(ushort4*)(wwb + (size_t)c * 128 + q * 4) = o;
  } else if (i < 65920) {
    int j = i - 65536;
    bcat[j] = (j < 128) ? tb[j] : (j < 256) ? pb[j - 128] : gb[j - 256];
  }
}

// ---------------------------------------------------------------------------
// Kernel 1: all three projections as one MFMA GEMM + FUSED 2x2 maxpool.
//   x [B][512][N] fp32, wcat [384][512] bf16
//   -> theta_t [B][N][128], phi_t [B][M][128], gbuf [B][128][M] (all bf16).
// grid (N/128 = 32 h2, B), 512 threads (8 waves x 16 n-rows).
// Block h2 covers spatial rows 2h2, 2h2+1 -> exactly pooled row h2.
// A-frags (x): per-lane dword loads direct to regs + in-reg f2bf (no LDS).
// B-tiles (W): [384][64] bf16 per K-chunk, double-buffered global_load_lds
// with pre-swizzled source; one barrier per chunk.
// ---------------------------------------------------------------------------
__global__ __launch_bounds__(512) void k_conv_all(
    const float* __restrict__ x, const unsigned short* __restrict__ wcat,
    const float* __restrict__ bcat,
    unsigned short* __restrict__ theta_t, unsigned short* __restrict__ phi_t,
    unsigned short* __restrict__ gbuf) {
  __shared__ __align__(16) char smem[98304];   // W dbuf [2][49152]; epilogue alias
  const int b = blockIdx.y, h2 = blockIdx.x, n0 = h2 * 128;
  const int t = threadIdx.x;
  const int w = t >> 6, l = t & 63, lr = l & 15, lg = l >> 4;

  // per-lane pre-swizzled W staging source offsets (bytes):
  const char* wsrc = (const char*)wcat;   // row stride 1024 B
  int woff[6];
#pragma unroll
  for (int i = 0; i < 6; ++i) {
    int r = (w * 6 + i) * 8 + (l >> 3);
    woff[i] = r * 1024 + (((l & 7) * 16) ^ ((r & 7) << 4));
  }

  // x base for this lane's A-row: n = n0 + w*16 + lr
  const float* xb = x + (size_t)b * Cc * Nc + n0 + w * 16 + lr;

  float xraw[16];
#define LOADX(k0_)                                                        \
  {                                                                       \
    _Pragma("unroll")                                                     \
    for (int ks = 0; ks < 2; ++ks)                                        \
      _Pragma("unroll")                                                   \
      for (int j = 0; j < 8; ++j)                                         \
        xraw[ks * 8 + j] = xb[(size_t)((k0_) + ks * 32 + lg * 8 + j) * Nc]; \
  }
#define STAGEW(buf_, k0_)                                                 \
  {                                                                       \
    char* dst_ = smem + (buf_) * 49152;                                   \
    _Pragma("unroll")                                                     \
    for (int i = 0; i < 6; ++i)                                           \
      gload16(wsrc + (size_t)(k0_) * 2 + woff[i], dst_ + (w * 6 + i) * 1024); \
  }

  f32x4 acc[24];
#pragma unroll
  for (int tc = 0; tc < 24; ++tc) acc[tc] = (f32x4){0.f, 0.f, 0.f, 0.f};

  // prologue
  LOADX(0);
  STAGEW(0, 0);
  asm volatile("s_waitcnt vmcnt(0)" ::: "memory");
  __builtin_amdgcn_s_barrier();

  for (int c = 0; c < 8; ++c) {
    const int cur = c & 1;
    bf16x8 af[2];
#pragma unroll
    for (int ks = 0; ks < 2; ++ks) {
      union { unsigned u[4]; bf16x8 v; } ab;
#pragma unroll
      for (int q = 0; q < 4; ++q)
        ab.u[q] = pack2bf(xraw[ks * 8 + 2 * q], xraw[ks * 8 + 2 * q + 1]);
      af[ks] = ab.v;
    }
    if (c < 7) {
      LOADX((c + 1) * 64);
      STAGEW(cur ^ 1, (c + 1) * 64);
    }
    const char* Wb = smem + cur * 49152;
    __builtin_amdgcn_s_setprio(1);
#pragma unroll
    for (int ks = 0; ks < 2; ++ks)
#pragma unroll
      for (int tc = 0; tc < 24; ++tc) {
        int r = tc * 16 + lr;
        bf16x8 bfr = *(const bf16x8*)(
            Wb + r * 128 + ((lg * 16 + ks * 64) ^ ((lr & 7) << 4)));
        acc[tc] = __builtin_amdgcn_mfma_f32_16x16x32_bf16(af[ks], bfr, acc[tc], 0, 0, 0);
      }
    __builtin_amdgcn_s_setprio(0);
    asm volatile("s_waitcnt vmcnt(0)" ::: "memory");
    __builtin_amdgcn_s_barrier();
  }
#undef LOADX
#undef STAGEW

  // ---- epilogue ----
  // PG strip: [128 rows][264 ushort] (phi cols 0-127, g cols 128-255)
  // Yt strip: [64 rows][136 ushort] theta (per half)
  unsigned short* PG = (unsigned short*)smem;            // 67584 B
  unsigned short* Yt = (unsigned short*)(smem + 67584);  // 17408 B
  const int rbase = w * 16 + lg * 4;   // local row base for (this wave, lg)

  // phase 1: phi/g -> PG (all waves); theta half-0 -> Yt (waves 0-3)
#pragma unroll
  for (int tc = 8; tc < 24; ++tc) {
    float bv = bcat[tc * 16 + lr];
#pragma unroll
    for (int reg = 0; reg < 4; ++reg)
      PG[(rbase + reg) * 264 + tc * 16 + lr - 128] = f2bf(acc[tc][reg] + bv);
  }
  if (w < 4) {
#pragma unroll
    for (int tc = 0; tc < 8; ++tc) {
      float bv = bcat[tc * 16 + lr];
#pragma unroll
      for (int reg = 0; reg < 4; ++reg)
        Yt[(rbase + reg) * 136 + tc * 16 + lr] = f2bf(acc[tc][reg] + bv);
    }
  }
  __syncthreads();
  // theta half-0 global write
#pragma unroll
  for (int it = 0; it < 2; ++it) {
    int idx = it * 512 + t, n = idx >> 4, j = idx & 15;
    *(bf16x8*)(theta_t + (((size_t)(b * Nc + n0 + n)) << 7) + j * 8) =
        *(const bf16x8*)(Yt + n * 136 + j * 8);
  }
  // pooled phi: [32 m][128 ci], thread t: mloc=t>>4, j=t&15
  {
    int mloc = t >> 4, j = t & 15;
    const unsigned short* r0 = &PG[(2 * mloc) * 264 + j * 8];
    const unsigned short* r1 = &PG[(2 * mloc + 1) * 264 + j * 8];
    const unsigned short* r2 = &PG[(64 + 2 * mloc) * 264 + j * 8];
    const unsigned short* r3 = &PG[(65 + 2 * mloc) * 264 + j * 8];
    unsigned short o[8];
#pragma unroll
    for (int q = 0; q < 8; ++q)
      o[q] = f2bf(fmaxf(fmaxf(bf2f(r0[q]), bf2f(r1[q])),
                        fmaxf(bf2f(r2[q]), bf2f(r3[q]))));
    unsigned short* dp = phi_t + (((size_t)(b * Mc + h2 * 32 + mloc)) << 7) + j * 8;
    *(ushort4*)dp = *(ushort4*)o;
    *(ushort4*)(dp + 4) = *(ushort4*)(o + 4);
  }
  // pooled g (transposed): thread t: ci=t>>2, mq=t&3 (8 m each)
  {
    int ci = t >> 2, mq = t & 3;
    unsigned short tmp[8];
#pragma unroll
    for (int q = 0; q < 8; ++q) {
      int w2 = mq * 8 + q;
      float m0 = fmaxf(
          fmaxf(bf2f(PG[(2 * w2) * 264 + 128 + ci]),
                bf2f(PG[(2 * w2 + 1) * 264 + 128 + ci])),
          fmaxf(bf2f(PG[(64 + 2 * w2) * 264 + 128 + ci]),
                bf2f(PG[(65 + 2 * w2) * 264 + 128 + ci])));
      tmp[q] = f2bf(m0);
    }
    unsigned short* dst = gbuf + ((size_t)(b * CIc + ci)) * Mc + h2 * 32 + mq * 8;
    *(ushort4*)(dst) = *(ushort4*)(tmp);
    *(ushort4*)(dst + 4) = *(ushort4*)(tmp + 4);
  }
  __syncthreads();
  // theta half-1 -> Yt (waves 4-7), then global write
  if (w >= 4) {
#pragma unroll
    for (int tc = 0; tc < 8; ++tc) {
      float bv = bcat[tc * 16 + lr];
#pragma unroll
      for (int reg = 0; reg < 4; ++reg)
        Yt[((w - 4) * 16 + lg * 4 + reg) * 136 + tc * 16 + lr] =
            f2bf(acc[tc][reg] + bv);
    }
  }
  __syncthreads();
#pragma unroll
  for (int it = 0; it < 2; ++it) {
    int idx = it * 512 + t, n = idx >> 4, j = idx & 15;
    *(bf16x8*)(theta_t + (((size_t)(b * Nc + n0 + 64 + n)) << 7) + j * 8) =
        *(const bf16x8*)(Yt + n * 136 + j * 8);
  }
}

// ---------------------------------------------------------------------------
// Kernel 3: MFMA flash attention, double-buffered async staging.
// This round: softmax VALU cut — v_cvt_pk_bf16_f32 for P->bf16 (8 ops vs
// 64) + defer-max (skip rescale unless any row's max grew by >8).
// ---------------------------------------------------------------------------
__global__ __launch_bounds__(256) void k_attn_mfma(
    const unsigned short* __restrict__ theta_t,
    const unsigned short* __restrict__ phi_t,
    const unsigned short* __restrict__ gv,
    unsigned short* __restrict__ y_t) {
  __shared__ __align__(16) char Kb[2][16384];   // [64 m][256B] swizzled
  __shared__ __align__(16) char Vb[2][16384];   // [128 ci][128B] swizzled
  __shared__ __align__(16) unsigned short Ps[4][16][72];  // per-wave P tile
  const int b = blockIdx.y, n0 = blockIdx.x * 64;
  const int tid = threadIdx.x;
  const int w = tid >> 6, l = tid & 63;
  const int lr = l & 15, lg = l >> 4;

  const int krow_l = l >> 4, kchunk = (l & 15) * 16;
  const int vrow_l = l >> 3, vchunk = (l & 7) * 16;
  int koff[4], voff[4];
#pragma unroll
  for (int i = 0; i < 4; ++i) {
    int kr = w * 16 + i * 4 + krow_l;
    koff[i] = kr * 256 + (kchunk ^ ((kr & 7) << 4));
    int vr = w * 32 + i * 8 + vrow_l;
    voff[i] = vr * 2048 + (vchunk ^ ((vr & 7) << 4));
  }
  const char* kbase = (const char*)(phi_t + (((size_t)(b * Mc)) << 7));
  const char* vbase = (const char*)(gv + (((size_t)b) << 17));

  auto stage = [&](int buf, int t) {
#pragma unroll
    for (int i = 0; i < 4; ++i)
      gload16(kbase + t * 16384 + koff[i], &Kb[buf][(w * 4 + i) * 1024]);
#pragma unroll
    for (int i = 0; i < 4; ++i)
      gload16(vbase + t * 128 + voff[i], &Vb[buf][(w * 4 + i) * 1024]);
  };

  bf16x8 qf[4];
  {
    const unsigned short* qp =
        theta_t + (((size_t)(b * Nc + n0 + w * 16 + lr)) << 7);
#pragma unroll
    for (int kk = 0; kk < 4; ++kk)
      qf[kk] = *(const bf16x8*)(qp + kk * 32 + lg * 8);
  }
  f32x4 of[8];
#pragma unroll
  for (int ct = 0; ct < 8; ++ct) of[ct] = (f32x4){0.f, 0.f, 0.f, 0.f};
  float run_m[4], run_l[4];
#pragma unroll
  for (int r = 0; r < 4; ++r) { run_m[r] = -1e30f; run_l[r] = 0.f; }

  stage(0, 0);
  asm volatile("s_waitcnt vmcnt(0)" ::: "memory");
  __builtin_amdgcn_s_barrier();

  for (int t = 0; t < Mc / 64; ++t) {
    const int cur = t & 1;
    if (t + 1 < Mc / 64) stage(cur ^ 1, t + 1);
    const char* Ks = Kb[cur];
    const char* Vs = Vb[cur];
    f32x4 sm[4];
    __builtin_amdgcn_s_setprio(1);
#pragma unroll
    for (int mt = 0; mt < 4; ++mt) {
      f32x4 s = (f32x4){0.f, 0.f, 0.f, 0.f};
#pragma unroll
      for (int kk = 0; kk < 4; ++kk) {
        bf16x8 kf = *(const bf16x8*)(
            Ks + (mt * 16 + lr) * 256 + ((kk * 64 + lg * 16) ^ ((lr & 7) << 4)));
        s = __builtin_amdgcn_mfma_f32_16x16x32_bf16(qf[kk], kf, s, 0, 0, 0);
      }
      sm[mt] = s;
    }
    __builtin_amdgcn_s_setprio(0);
    // ---- online softmax with defer-max ----
    float pmax[4];
#pragma unroll
    for (int reg = 0; reg < 4; ++reg) {
      float mx = fmaxf(fmaxf(sm[0][reg], sm[1][reg]), fmaxf(sm[2][reg], sm[3][reg]));
      mx = fmaxf(mx, __shfl_xor(mx, 1));
      mx = fmaxf(mx, __shfl_xor(mx, 2));
      mx = fmaxf(mx, __shfl_xor(mx, 4));
      mx = fmaxf(mx, __shfl_xor(mx, 8));
      pmax[reg] = mx;
    }
    bool need = (pmax[0] > run_m[0] + 8.f) | (pmax[1] > run_m[1] + 8.f) |
                (pmax[2] > run_m[2] + 8.f) | (pmax[3] > run_m[3] + 8.f);
    if (__any(need)) {
#pragma unroll
      for (int reg = 0; reg < 4; ++reg) {
        float nm = fmaxf(run_m[reg], pmax[reg]);
        float sc = __expf(run_m[reg] - nm);
        run_m[reg] = nm;
        run_l[reg] *= sc;
#pragma unroll
        for (int ct = 0; ct < 8; ++ct) of[ct][reg] *= sc;
      }
    }
#pragma unroll
    for (int reg = 0; reg < 4; ++reg) {
      float p0 = __expf(sm[0][reg] - run_m[reg]);
      float p1 = __expf(sm[1][reg] - run_m[reg]);
      float p2 = __expf(sm[2][reg] - run_m[reg]);
      float p3 = __expf(sm[3][reg] - run_m[reg]);
      unsigned pk01, pk23;
      asm("v_cvt_pk_bf16_f32 %0, %1, %2" : "=v"(pk01) : "v"(p0), "v"(p1));
      asm("v_cvt_pk_bf16_f32 %0, %1, %2" : "=v"(pk23) : "v"(p2), "v"(p3));
      unsigned short* pr = &Ps[w][lg * 4 + reg][lr];
      pr[0]  = (unsigned short)pk01;          // mt=0
      pr[16] = (unsigned short)(pk01 >> 16);  // mt=1
      pr[32] = (unsigned short)pk23;          // mt=2
      pr[48] = (unsigned short)(pk23 >> 16);  // mt=3
      float rs = (p0 + p1) + (p2 + p3);
      rs += __shfl_xor(rs, 1);
      rs += __shfl_xor(rs, 2);
      rs += __shfl_xor(rs, 4);
      rs += __shfl_xor(rs, 8);
      run_l[reg] += rs;
    }
    bf16x8 pa0 = *(const bf16x8*)(&Ps[w][lr][lg * 8]);
    bf16x8 pa1 = *(const bf16x8*)(&Ps[w][lr][32 + lg * 8]);
    __builtin_amdgcn_s_setprio(1);
#pragma unroll
    for (int ct = 0; ct < 8; ++ct) {
      bf16x8 vf0 = *(const bf16x8*)(
          Vs + (ct * 16 + lr) * 128 + ((lg * 16) ^ ((lr & 7) << 4)));
      of[ct] = __builtin_amdgcn_mfma_f32_16x16x32_bf16(pa0, vf0, of[ct], 0, 0, 0);
      bf16x8 vf1 = *(const bf16x8*)(
          Vs + (ct * 16 + lr) * 128 + ((64 + lg * 16) ^ ((lr & 7) << 4)));
      of[ct] = __builtin_amdgcn_mfma_f32_16x16x32_bf16(pa1, vf1, of[ct], 0, 0, 0);
    }
    __builtin_amdgcn_s_setprio(0);
    asm volatile("s_waitcnt vmcnt(0)" ::: "memory");
    __builtin_amdgcn_s_barrier();
  }
  float invl[4];
#pragma unroll
  for (int reg = 0; reg < 4; ++reg) invl[reg] = 1.f / run_l[reg];
  unsigned short* Ys = (unsigned short*)Kb;
#pragma unroll
  for (int ct = 0; ct < 8; ++ct)
#pragma unroll
    for (int reg = 0; reg < 4; ++reg)
      Ys[(w * 16 + lg * 4 + reg) * 128 + ct * 16 + lr] =
          f2bf(of[ct][reg] * invl[reg]);
  __syncthreads();
#pragma unroll
  for (int it = 0; it < 4; ++it) {
    int i = it * 256 + tid;
    int r = i >> 4, cl = i & 15;
    *(bf16x8*)(y_t + (((size_t)(b * Nc + n0 + r)) << 7) + cl * 8) =
        *(const bf16x8*)(Ys + r * 128 + cl * 8);
  }
}

// ---------------------------------------------------------------------------
// Kernel 4: MFMA W-conv + channels-first LayerNorm + residual (unchanged).
// ---------------------------------------------------------------------------
__global__ __launch_bounds__(256) void k_wconv_mfma(
    const unsigned short* __restrict__ y_t, const unsigned short* __restrict__ wwb,
    const float* __restrict__ wbias, const float* __restrict__ gamma,
    const float* __restrict__ beta, const float* __restrict__ x,
    float* __restrict__ out) {
  __shared__ __align__(16) char smem[36864];
  unsigned short* WTs = (unsigned short*)smem;  // [128][128] swizzled 256B rows
  float* Ys = (float*)smem;                     // epilogue alias [128 c][72 n]
  const int b = blockIdx.y, n0 = blockIdx.x * 64;
  const int t = threadIdx.x;
  const int w = t >> 6, l = t & 63, lr = l & 15, lg = l >> 4;

  bf16x8 qf[4];
  {
    const unsigned short* qp = y_t + (((size_t)(b * Nc + n0 + w * 16 + lr)) << 7);
#pragma unroll
    for (int kk = 0; kk < 4; ++kk)
      qf[kk] = *(const bf16x8*)(qp + kk * 32 + lg * 8);
  }
  f32x4 acc[32];
#pragma unroll
  for (int i = 0; i < 32; ++i) acc[i] = (f32x4){0.f, 0.f, 0.f, 0.f};

#pragma unroll
  for (int cc = 0; cc < 4; ++cc) {
    __syncthreads();
#pragma unroll
    for (int it = 0; it < 8; ++it) {
      int i = it * 256 + t;
      int r = i >> 4, j = i & 15;
      bf16x8 v = *(const bf16x8*)(wwb + (((size_t)(cc * 128 + r)) << 7) + j * 8);
      *(bf16x8*)((char*)WTs + r * 256 + ((j * 16) ^ ((r & 7) << 4))) = v;
    }
    __syncthreads();
#pragma unroll
    for (int tc = 0; tc < 8; ++tc) {
      f32x4 a = acc[cc * 8 + tc];
      int r = tc * 16 + lr;
#pragma unroll
      for (int kk = 0; kk < 4; ++kk) {
        bf16x8 kf = *(const bf16x8*)(
            (char*)WTs + r * 256 + ((kk * 64 + lg * 16) ^ ((lr & 7) << 4)));
        a = __builtin_amdgcn_mfma_f32_16x16x32_bf16(qf[kk], kf, a, 0, 0, 0);
      }
      acc[cc * 8 + tc] = a;
    }
  }
  float s[4] = {0.f, 0.f, 0.f, 0.f}, q[4] = {0.f, 0.f, 0.f, 0.f};
#pragma unroll
  for (int cc = 0; cc < 4; ++cc)
#pragma unroll
    for (int tc = 0; tc < 8; ++tc) {
      float wb = wbias[cc * 128 + tc * 16 + lr];
      f32x4 a = acc[cc * 8 + tc];
#pragma unroll
      for (int reg = 0; reg < 4; ++reg) {
        a[reg] += wb;
        s[reg] += a[reg];
        q[reg] += a[reg] * a[reg];
      }
      acc[cc * 8 + tc] = a;
    }
  float mu[4], rs[4];
#pragma unroll
  for (int reg = 0; reg < 4; ++reg) {
    float sv = s[reg], qv = q[reg];
    sv += __shfl_xor(sv, 1); qv += __shfl_xor(qv, 1);
    sv += __shfl_xor(sv, 2); qv += __shfl_xor(qv, 2);
    sv += __shfl_xor(sv, 4); qv += __shfl_xor(qv, 4);
    sv += __shfl_xor(sv, 8); qv += __shfl_xor(qv, 8);
    mu[reg] = sv * (1.f / 512.f);
    float var = qv * (1.f / 512.f) - mu[reg] * mu[reg];
    rs[reg] = rsqrtf(var + 1e-5f);
  }
#pragma unroll
  for (int cc = 0; cc < 4; ++cc) {
    __syncthreads();
#pragma unroll
    for (int tc = 0; tc < 8; ++tc) {
      int c = cc * 128 + tc * 16 + lr;
      float ga = gamma[c], be = beta[c];
#pragma unroll
      for (int reg = 0; reg < 4; ++reg)
        Ys[(tc * 16 + lr) * 72 + w * 16 + lg * 4 + reg] =
            (acc[cc * 8 + tc][reg] - mu[reg]) * rs[reg] * ga + be;
    }
    __syncthreads();
#pragma unroll
    for (int it = 0; it < 8; ++it) {
      int idx = it * 256 + t;
      int r = idx >> 4, j = idx & 15;
      float4 v = *(const float4*)&Ys[r * 72 + j * 4];
      size_t gaddr = ((size_t)b * Cc + cc * 128 + r) * Nc + n0 + j * 4;
      float4 xv = *(const float4*)&x[gaddr];
      float4 o;
      o.x = v.x + xv.x; o.y = v.y + xv.y; o.z = v.z + xv.z; o.w = v.w + xv.w;
      *(float4*)&out[gaddr] = o;
    }
  }
}

// ---------------------------------------------------------------------------
extern "C" void kernel_launch(void* const* d_in, const int* in_sizes, int n_in,
                              void* d_out, int out_size, void* d_ws, size_t ws_size,
                              hipStream_t stream) {
  const float* x       = (const float*)d_in[0];
  const float* g_w     = (const float*)d_in[1];
  const float* g_b     = (const float*)d_in[2];
  const float* phi_w   = (const float*)d_in[3];
  const float* phi_b   = (const float*)d_in[4];
  const float* theta_w = (const float*)d_in[5];
  const float* theta_b = (const float*)d_in[6];
  const float* W_w     = (const float*)d_in[7];
  const float* W_b     = (const float*)d_in[8];
  const float* ln_g    = (const float*)d_in[9];
  const float* ln_b    = (const float*)d_in[10];
  float* out = (float*)d_out;

  // ws layout (ushort): theta_t [B,N,128] | y_t [B,N,128] | phi_t [B,M,128]
  //                     | gbuf [B,128,M] | wcat | wwb | bcat f32
  unsigned short* theta_t = (unsigned short*)d_ws;
  unsigned short* y_t     = theta_t + (size_t)Bc * Nc * CIc;
  unsigned short* phi_t   = y_t + (size_t)Bc * Nc * CIc;
  unsigned short* gbuf    = phi_t + (size_t)Bc * Mc * CIc;
  unsigned short* wcat    = gbuf + (size_t)Bc * Mc * CIc;
  unsigned short* wwb     = wcat + (size_t)384 * 512;
  float*          bcat    = (float*)(wwb + (size_t)512 * 128);

  k_prep<<<dim3(258), dim3(256), 0, stream>>>(
      g_w, phi_w, theta_w, W_w, g_b, phi_b, theta_b, wcat, wwb, bcat);
  k_conv_all<<<dim3(Nc / 128, Bc), dim3(512), 0, stream>>>(
      x, wcat, bcat, theta_t, phi_t, gbuf);
  k_attn_mfma<<<dim3(Nc / 64, Bc), dim3(256), 0, stream>>>(
      theta_t, phi_t, gbuf, y_t);
  k_wconv_mfma<<<dim3(Nc / 64, Bc), dim3(256), 0, stream>>>(
      y_t, wwb, W_b, ln_g, ln_b, x, out);
}